// Round 1
// baseline (472.172 us; speedup 1.0000x reference)
//
#include <hip/hip_runtime.h>
#include <hip/hip_fp16.h>
#include <math.h>

#define D_MODEL 1024
#define NH 16
#define HD 64
#define SEQ 2048
#define BATCH 2
#define MROWS (BATCH*SEQ)   // 4096
#define KDIM 1024

typedef unsigned short u16;
typedef __attribute__((ext_vector_type(8))) _Float16 h8;   // 8 f16 (4 VGPRs)
typedef __attribute__((ext_vector_type(8))) short s8v;
typedef __attribute__((ext_vector_type(4))) float f4v;

#define MFMAH(a, b, c) __builtin_amdgcn_mfma_f32_16x16x32_f16(a, b, c, 0, 0, 0)

__device__ __forceinline__ u16 f32_to_f16(float f) {
    return __half_as_ushort(__float2half(f));   // v_cvt_f16_f32, RNE
}
__device__ __forceinline__ float f16_to_f32(u16 h) {
    return __half2float(__ushort_as_half(h));
}

// ---------------------------------------------------------------------------
// fp32 -> fp16 conversion for x (4M) + 4 W (1M each). 8 elems/thread.
// Single 16B store per thread: per-instruction 1KB contiguous wave footprint.
// ---------------------------------------------------------------------------
__global__ __launch_bounds__(256)
void convert_f16(const float* __restrict__ x,
                 const float* __restrict__ Wq, const float* __restrict__ Wk,
                 const float* __restrict__ Wv, const float* __restrict__ Wo,
                 u16* __restrict__ xF,
                 u16* __restrict__ WqF, u16* __restrict__ WkF,
                 u16* __restrict__ WvF, u16* __restrict__ WoF) {
    int i = blockIdx.x * 256 + threadIdx.x;
    const float* src;
    u16* dst;
    int idx;
    if (i < (1 << 19)) {
        src = x; dst = xF; idx = i;
    } else {
        int j = i - (1 << 19);
        int w = j >> 17;
        idx = j & ((1 << 17) - 1);
        switch (w) {
            case 0:  src = Wq; dst = WqF; break;
            case 1:  src = Wk; dst = WkF; break;
            case 2:  src = Wv; dst = WvF; break;
            default: src = Wo; dst = WoF; break;
        }
    }
    float4 a = ((const float4*)src)[idx * 2];
    float4 b = ((const float4*)src)[idx * 2 + 1];
    s8v o;
    o[0] = (short)f32_to_f16(a.x); o[1] = (short)f32_to_f16(a.y);
    o[2] = (short)f32_to_f16(a.z); o[3] = (short)f32_to_f16(a.w);
    o[4] = (short)f32_to_f16(b.x); o[5] = (short)f32_to_f16(b.y);
    o[6] = (short)f32_to_f16(b.z); o[7] = (short)f32_to_f16(b.w);
    ((s8v*)dst)[idx] = o;
}

// ---------------------------------------------------------------------------
// Fused QKV fp16 MFMA GEMM, explicit staging, XCD-swizzled 1D grid (768).
// Q,K: fused RoPE -> LDS-staged tile -> 16B/lane coalesced fp16 stores
// (full 128B lines per instruction; fixes 50x write amplification of the
// old per-lane 2B scalar stores). K: atomicMax row-norm^2 (RoPE-invariant).
// V: LDS transpose -> fp16 [B,H,D,S], drain reordered so each store
// instruction covers full lines.
// ---------------------------------------------------------------------------
__global__ __launch_bounds__(256, 2)
void qkv_gemm(const u16* __restrict__ xF, const u16* __restrict__ WqF,
              const u16* __restrict__ WkF, const u16* __restrict__ WvF,
              const float* __restrict__ bq, const float* __restrict__ bk,
              const float* __restrict__ bv,
              u16* __restrict__ QF, u16* __restrict__ KF,
              u16* __restrict__ VtF, float* __restrict__ km2) {
    __shared__ __align__(16) u16 SMEM[16384];   // 32 KB; K-loop uses first 16 KB
    u16* As = SMEM;                 // [128][32] f16
    u16* Bs = SMEM + 4096;

    const int t    = threadIdx.x;
    const int w    = t >> 6;
    const int lane = t & 63;
    const int quad = lane >> 4;
    const int l15  = lane & 15;
    const int wr   = w >> 1;
    const int wc   = w & 1;

    // XCD-aware decode: xcd = bid&7 owns m-tiles [xcd*4, xcd*4+4)
    const int bid  = blockIdx.x;
    const int xcd  = bid & 7;
    const int j    = bid >> 3;          // 0..95
    const int m0b  = (xcd * 4 + (j & 3)) * 128;
    const int yt   = j >> 2;            // 0..23
    const int wsel = yt >> 3;
    const int n0   = (yt & 7) * 128;

    const u16* Bg;
    const float* bias;
    if (wsel == 0)      { Bg = WqF; bias = bq; }
    else if (wsel == 1) { Bg = WkF; bias = bk; }
    else                { Bg = WvF; bias = bv; }

    const int srow = t >> 2;            // 0..63
    const int scol = (t & 3) * 8;
    const u16* ag = xF + (size_t)(m0b + srow) * KDIM + scol;
    const u16* bg = Bg + (size_t)(n0 + srow) * KDIM + scol;
    const size_t rstep = (size_t)64 * KDIM;

    f4v acc[4][4];
    #pragma unroll
    for (int i = 0; i < 4; i++)
        #pragma unroll
        for (int jj = 0; jj < 4; jj++)
            acc[i][jj] = (f4v){0.f, 0.f, 0.f, 0.f};

    for (int k0 = 0; k0 < KDIM; k0 += 32) {
        s8v a0 = *(const s8v*)(ag + k0);
        s8v a1 = *(const s8v*)(ag + rstep + k0);
        s8v b0 = *(const s8v*)(bg + k0);
        s8v b1 = *(const s8v*)(bg + rstep + k0);
        __syncthreads();                 // prior iter's ds_reads done
        *(s8v*)&As[t * 8]         = a0;
        *(s8v*)&As[(256 + t) * 8] = a1;
        *(s8v*)&Bs[t * 8]         = b0;
        *(s8v*)&Bs[(256 + t) * 8] = b1;
        __syncthreads();

        h8 a[4], b[4];
        #pragma unroll
        for (int i = 0; i < 4; i++) {
            a[i] = *(const h8*)&As[(wr * 64 + i * 16 + l15) * 32 + quad * 8];
            b[i] = *(const h8*)&Bs[(wc * 64 + i * 16 + l15) * 32 + quad * 8];
        }
        #pragma unroll
        for (int mt = 0; mt < 4; mt++)
            #pragma unroll
            for (int nt = 0; nt < 4; nt++)
                acc[mt][nt] = MFMAH(a[mt], b[nt], acc[mt][nt]);
    }

    const int bb = m0b >> 11;
    const int s0 = m0b & 2047;
    const int h0 = n0 >> 6;             // first of 2 heads in this n-tile

    if (wsel < 2) {
        // ---- Q/K: fused RoPE -> LDS tile [128 s][128 n] swizzled ----
        u16* OF = (wsel == 0) ? QF : KF;
        float kn_max = 0.f;
        __syncthreads();                 // K-loop ds_reads done; SMEM reuse
        #pragma unroll
        for (int mt = 0; mt < 4; mt++) {
            #pragma unroll
            for (int r = 0; r < 4; r++) {
                int row = wr * 64 + mt * 16 + quad * 4 + r;   // local s
                int s = (m0b + row) & 2047;
                float rowsum = 0.f;
                #pragma unroll
                for (int nt = 0; nt < 2; nt++) {
                    int col = wc * 64 + nt * 16 + l15;        // local n
                    int n1 = n0 + col;
                    int dd = n1 & 31;
                    float v1 = acc[mt][nt][r]     + bias[n1];
                    float v2 = acc[mt][nt + 2][r] + bias[n1 + 32];
                    float inv = __expf(-(float)dd * 0.2878231366f); // 1e4^(-dd/32)
                    float ang = (float)s * inv;
                    float cs  = cosf(ang);
                    float sn  = sinf(ang);
                    float r1 = v1 * cs - v2 * sn;
                    float r2 = v2 * cs + v1 * sn;
                    rowsum += v1 * v1 + v2 * v2;     // norm is RoPE-invariant
                    SMEM[row * 128 + (((col >> 3) ^ (row & 15)) << 3) + (col & 7)]
                        = f32_to_f16(r1);
                    int col2 = col + 32;
                    SMEM[row * 128 + (((col2 >> 3) ^ (row & 15)) << 3) + (col2 & 7)]
                        = f32_to_f16(r2);
                }
                if (wsel == 1) {
                    rowsum += __shfl_xor(rowsum, 1, 64);
                    rowsum += __shfl_xor(rowsum, 2, 64);
                    rowsum += __shfl_xor(rowsum, 4, 64);
                    rowsum += __shfl_xor(rowsum, 8, 64);
                    kn_max = fmaxf(kn_max, rowsum);
                }
            }
        }
        if (wsel == 1) {
            kn_max = fmaxf(kn_max, __shfl_xor(kn_max, 16, 64));
            kn_max = fmaxf(kn_max, __shfl_xor(kn_max, 32, 64));
            if (lane == 0) atomicMax((int*)km2, __float_as_int(kn_max));
        }
        __syncthreads();
        // drain: thread covers 8 chunks; per instruction each wave writes
        // 1 KB contiguous in [B,H,S,D] (8 full 128B lines)
        #pragma unroll
        for (int cc = 0; cc < 8; cc++) {
            int idx  = cc * 256 + t;       // 0..2047
            int hl   = idx >> 10;          // 0..1
            int rem  = idx & 1023;
            int sr   = rem >> 3;           // local s 0..127
            int dch  = rem & 7;            // 16B chunk along d
            s8v val = *(const s8v*)&SMEM[sr * 128 +
                          (((hl * 8 + dch) ^ (sr & 15)) << 3)];
            *(s8v*)(OF + (((size_t)bb * NH + h0 + hl) * SEQ + s0 + sr) * 64
                       + dch * 8) = val;
        }
    } else {
        // ---- V: transpose via LDS, fp16 [B,H,D,S] ----
        __syncthreads();
        #pragma unroll
        for (int mt = 0; mt < 4; mt++) {
            #pragma unroll
            for (int nt = 0; nt < 4; nt++) {
                int n = wc * 64 + nt * 16 + l15;
                float bv_ = bias[n0 + n];
                #pragma unroll
                for (int r = 0; r < 4; r++) {
                    int m = wr * 64 + mt * 16 + quad * 4 + r;
                    float v = acc[mt][nt][r] + bv_;
                    SMEM[n * 128 + ((((m >> 3) ^ (n & 15))) << 3) + (m & 7)] = f32_to_f16(v);
                }
            }
        }
        __syncthreads();
        // drain reordered: per instruction a wave covers 4 full d-rows
        // (4 x 256B contiguous) instead of 64 scattered 16B fragments
        #pragma unroll
        for (int cc = 0; cc < 8; cc++) {
            int idx = cc * 256 + t;        // 0..2047
            int n   = idx >> 4;            // local col: h*64+d, 0..127
            int mc  = idx & 15;            // 16B chunk along s
            int d   = n & 63;
            int hh  = n >> 6;
            size_t obase = ((size_t)((bb * NH + h0 + hh) * HD + d)) * SEQ + s0;
            s8v val = *(const s8v*)&SMEM[n * 128 + ((mc ^ (n & 15)) << 3)];
            *(s8v*)(VtF + obase + mc * 8) = val;
        }
    }
}

// ---------------------------------------------------------------------------
// MFMA flash attention, fp16, static-bound softmax, Q-tile 128, 64 keys per
// barrier. XCD-swizzled 1D grid (512). Epilogue now LDS-staged (aliased onto
// dead K/V/P buffers, zero extra LDS) -> 16B/lane full-line stores.
// ---------------------------------------------------------------------------
__global__ __launch_bounds__(256, 4)
void flash_attn(const u16* __restrict__ QF, const u16* __restrict__ KF,
                const u16* __restrict__ VtF,
                const float* __restrict__ kmax2,
                u16* __restrict__ AOF) {
    __shared__ __align__(16) u16 SM[14848];
    // layout: KS[2][32*72] @0 (4608) | VtS[2][64*40] @4608 (5120) | PS @9728 (5120)
    #define KSp(sub) (SM + (sub) * 2304)
    #define VSp(sub) (SM + 4608 + (sub) * 2560)
    u16* PS = SM + 9728;

    const int t    = threadIdx.x;
    const int w    = t >> 6;
    const int lane = t & 63;
    const int quad = lane >> 4;
    const int l15  = lane & 15;

    const int bid = blockIdx.x;
    const int xcd = bid & 7;
    const int j   = bid >> 3;          // 0..63
    const int bh  = xcd * 4 + (j & 3); // 0..31
    const int q0  = (j >> 2) * 128;    // 0..15 * 128

    const size_t kvbase = (size_t)bh * SEQ * HD;
    const float km2 = kmax2[0];

    // ---- Q fragments for both row-tiles; static softmax bounds ----
    h8 qf[2][2];
    float m0[2][4];
    #pragma unroll
    for (int g = 0; g < 2; g++) {
        const u16* qp = QF + kvbase +
            (size_t)(q0 + g * 64 + w * 16 + l15) * HD + quad * 8;
        qf[g][0] = *(const h8*)qp;
        qf[g][1] = *(const h8*)(qp + 32);
        float qn2 = 0.f;
        #pragma unroll
        for (int st = 0; st < 2; st++)
            #pragma unroll
            for (int e = 0; e < 8; e++) {
                float v = (float)qf[g][st][e];
                qn2 += v * v;
            }
        qn2 += __shfl_xor(qn2, 16, 64);
        qn2 += __shfl_xor(qn2, 32, 64);
        #pragma unroll
        for (int r = 0; r < 4; r++) {
            int src = (lane & 48) | (quad * 4 + r);
            float qr = __shfl(qn2, src, 64);
            m0[g][r] = sqrtf(qr * km2) * 0.125f;
        }
    }

    f4v o[2][4];
    float lsum[2][4];
    #pragma unroll
    for (int g = 0; g < 2; g++)
        #pragma unroll
        for (int nt = 0; nt < 4; nt++) {
            o[g][nt] = (f4v){0.f, 0.f, 0.f, 0.f};
            lsum[g][nt] = 0.f;
        }

    for (int k0 = 0; k0 < SEQ; k0 += 64) {
        __syncthreads();

        // ---- stage two K subtiles (each 32 keys x 64 d) ----
        {
            int row = t >> 3;
            int dc  = (t & 7) * 8;
            *(s8v*)&KSp(0)[row * 72 + dc] =
                *(const s8v*)(KF + kvbase + (size_t)(k0 + row) * HD + dc);
            *(s8v*)&KSp(1)[row * 72 + dc] =
                *(const s8v*)(KF + kvbase + (size_t)(k0 + 32 + row) * HD + dc);
        }
        // ---- stage two V subtiles (64 d x 32 keys, swizzled) ----
        {
            int d  = t >> 2;
            int kc = (t & 3) * 8;
            size_t g = (size_t)bh * HD * SEQ + (size_t)d * SEQ + k0 + kc;
            int col = kc ^ (((d >> 3) & 3) << 3);
            *(s8v*)&VSp(0)[d * 40 + col] = *(const s8v*)(VtF + g);
            *(s8v*)&VSp(1)[d * 40 + col] = *(const s8v*)(VtF + g + 32);
        }
        __syncthreads();

        #pragma unroll
        for (int sub = 0; sub < 2; sub++) {
            const u16* kb0 = KSp(sub) + l15 * 72 + quad * 8;
            const u16* kb1 = KSp(sub) + (16 + l15) * 72 + quad * 8;
            h8 kh0 = *(const h8*)kb0, kh1 = *(const h8*)(kb0 + 32);
            h8 kh2 = *(const h8*)kb1, kh3 = *(const h8*)(kb1 + 32);

            #pragma unroll
            for (int g = 0; g < 2; g++) {
                f4v s0 = (f4v){0.f, 0.f, 0.f, 0.f};
                f4v s1 = (f4v){0.f, 0.f, 0.f, 0.f};
                s0 = MFMAH(qf[g][0], kh0, s0);
                s0 = MFMAH(qf[g][1], kh1, s0);
                s1 = MFMAH(qf[g][0], kh2, s1);
                s1 = MFMAH(qf[g][1], kh3, s1);

                #pragma unroll
                for (int r = 0; r < 4; r++) {
                    float p0 = __expf(s0[r] * 0.125f - m0[g][r]);
                    float p1 = __expf(s1[r] * 0.125f - m0[g][r]);
                    lsum[g][r] += p0 + p1;
                    int row_l = g * 64 + w * 16 + quad * 4 + r;
                    int cs = row_l & 8;
                    PS[row_l * 40 + (l15 ^ cs)]        = f32_to_f16(p0);
                    PS[row_l * 40 + ((16 + l15) ^ cs)] = f32_to_f16(p1);
                }

                const int prow = g * 64 + w * 16 + l15;
                h8 ph = *(const h8*)&PS[prow * 40 + ((quad * 8) ^ (prow & 8))];
                #pragma unroll
                for (int nt = 0; nt < 4; nt++) {
                    int dim = nt * 16 + l15;
                    int voff = dim * 40 + ((quad * 8) ^ (((dim >> 3) & 3) << 3));
                    o[g][nt] = MFMAH(ph, *(const h8*)&VSp(sub)[voff], o[g][nt]);
                }
            }
        }
    }

    // ---- epilogue: reduce l, normalize, LDS-stage, full-line fp16 stores ----
    const int b = bh >> 4;
    const int h = bh & 15;
    u16* OS = SM;                       // 128 x 64 u16 = 16 KB, aliases K/V/P
    __syncthreads();                    // all waves done with KS/VtS/PS
    #pragma unroll
    for (int g = 0; g < 2; g++) {
        #pragma unroll
        for (int r = 0; r < 4; r++) {
            float l = lsum[g][r];
            l += __shfl_xor(l, 1, 64);
            l += __shfl_xor(l, 2, 64);
            l += __shfl_xor(l, 4, 64);
            l += __shfl_xor(l, 8, 64);
            float inv_l = 1.0f / l;
            int row = g * 64 + w * 16 + quad * 4 + r;
            #pragma unroll
            for (int nt = 0; nt < 4; nt++) {
                int d = nt * 16 + l15;
                OS[row * 64 + (((d >> 3) ^ (row & 7)) << 3) + (d & 7)]
                    = f32_to_f16(o[g][nt][r] * inv_l);
            }
        }
    }
    __syncthreads();
    // per instruction: wave covers 8 full 128B lines of [B,S,H,D]
    #pragma unroll
    for (int cc = 0; cc < 4; cc++) {
        int idx = cc * 256 + t;        // 0..1023
        int sr  = idx >> 3;            // 0..127
        int dch = idx & 7;
        s8v val = *(const s8v*)&OS[sr * 64 + ((dch ^ (sr & 7)) << 3)];
        *(s8v*)(AOF + (((size_t)b * SEQ + q0 + sr) * NH + h) * 64 + dch * 8) = val;
    }
    #undef KSp
    #undef VSp
}

// ---------------------------------------------------------------------------
// Out-projection fp16 MFMA GEMM. Epilogue: two-pass LDS stage (32 KB) ->
// float4 stores, 8 full lines per wave instruction.
// ---------------------------------------------------------------------------
__global__ __launch_bounds__(256, 2)
void gemm_out(const u16* __restrict__ AF, const u16* __restrict__ BF,
              const float* __restrict__ bias, float* __restrict__ out) {
    __shared__ __align__(16) u16 SMEM[16384];   // 32 KB
    u16* As = SMEM;                 // [128][32] f16
    u16* Bs = SMEM + 4096;

    const int t    = threadIdx.x;
    const int w    = t >> 6;
    const int lane = t & 63;
    const int quad = lane >> 4;
    const int l15  = lane & 15;
    const int wr   = w >> 1;
    const int wc   = w & 1;

    const int bid = blockIdx.x;
    const int xcd = bid & 7;
    const int j   = bid >> 3;              // 0..31
    const int m0  = (xcd * 4 + (j & 3)) * 128;
    const int n0  = (j >> 2) * 128;        // 0..7 * 128

    const int srow = t >> 2;
    const int scol = (t & 3) * 8;
    const u16* ag = AF + (size_t)(m0 + srow) * KDIM + scol;
    const u16* bg = BF + (size_t)(n0 + srow) * KDIM + scol;
    const size_t rstep = (size_t)64 * KDIM;

    f4v acc[4][4];
    #pragma unroll
    for (int i = 0; i < 4; i++)
        #pragma unroll
        for (int jj = 0; jj < 4; jj++)
            acc[i][jj] = (f4v){0.f, 0.f, 0.f, 0.f};

    for (int k0 = 0; k0 < KDIM; k0 += 32) {
        s8v a0 = *(const s8v*)(ag + k0);
        s8v a1 = *(const s8v*)(ag + rstep + k0);
        s8v b0 = *(const s8v*)(bg + k0);
        s8v b1 = *(const s8v*)(bg + rstep + k0);
        __syncthreads();
        *(s8v*)&As[t * 8]         = a0;
        *(s8v*)&As[(256 + t) * 8] = a1;
        *(s8v*)&Bs[t * 8]         = b0;
        *(s8v*)&Bs[(256 + t) * 8] = b1;
        __syncthreads();

        h8 a[4], b[4];
        #pragma unroll
        for (int i = 0; i < 4; i++) {
            a[i] = *(const h8*)&As[(wr * 64 + i * 16 + l15) * 32 + quad * 8];
            b[i] = *(const h8*)&Bs[(wc * 64 + i * 16 + l15) * 32 + quad * 8];
        }
        #pragma unroll
        for (int mt = 0; mt < 4; mt++)
            #pragma unroll
            for (int nt = 0; nt < 4; nt++)
                acc[mt][nt] = MFMAH(a[mt], b[nt], acc[mt][nt]);
    }

    // two-pass epilogue: wr==p waves stage 64x128 f32 (32 KB), all drain
    float* OS = (float*)SMEM;
    #pragma unroll
    for (int p = 0; p < 2; p++) {
        __syncthreads();
        if (wr == p) {
            #pragma unroll
            for (int mt = 0; mt < 4; mt++) {
                #pragma unroll
                for (int nt = 0; nt < 4; nt++) {
                    int colL = wc * 64 + nt * 16 + l15;
                    float bv = bias[n0 + colL];
                    int ch = colL >> 2;
                    #pragma unroll
                    for (int r = 0; r < 4; r++) {
                        int row = mt * 16 + quad * 4 + r;   // 0..63
                        OS[row * 128 + ((ch ^ (row & 7)) << 2) + (colL & 3)]
                            = acc[mt][nt][r] + bv;
                    }
                }
            }
        }
        __syncthreads();
        #pragma unroll
        for (int cc = 0; cc < 8; cc++) {
            int idx = cc * 256 + t;        // 0..2047
            int row = idx >> 5;            // 0..63
            int ch  = idx & 31;
            float4 v = *(const float4*)&OS[row * 128 + ((ch ^ (row & 7)) << 2)];
            *(float4*)(out + (size_t)(m0 + p * 64 + row) * 1024 + n0 + ch * 4) = v;
        }
    }
}

// ---------------------------------------------------------------------------
extern "C" void kernel_launch(void* const* d_in, const int* in_sizes, int n_in,
                              void* d_out, int out_size, void* d_ws, size_t ws_size,
                              hipStream_t stream) {
    const float* x  = (const float*)d_in[0];
    const float* Wq = (const float*)d_in[1];
    const float* bq = (const float*)d_in[2];
    const float* Wk = (const float*)d_in[3];
    const float* bk = (const float*)d_in[4];
    const float* Wv = (const float*)d_in[5];
    const float* bv = (const float*)d_in[6];
    const float* Wo = (const float*)d_in[7];
    const float* bo = (const float*)d_in[8];
    float* out = (float*)d_out;

    const size_t TEN = (size_t)MROWS * KDIM;     // 4,194,304
    const size_t WSZ = (size_t)KDIM * KDIM;      // 1,048,576

    u16* xF  = (u16*)d_ws;
    u16* WqF = xF + TEN;
    u16* WkF = WqF + WSZ;
    u16* WvF = WkF + WSZ;
    u16* WoF = WvF + WSZ;
    u16* QF  = WoF + WSZ;
    u16* KF  = QF + TEN;
    u16* VtF = KF + TEN;
    float* km2 = (float*)(VtF + TEN);
    u16* AOF = xF;          // x dead after qkv_gemm

    convert_f16<<<4096, 256, 0, stream>>>(x, Wq, Wk, Wv, Wo,
                                          xF, WqF, WkF, WvF, WoF);

    hipMemsetAsync(km2, 0, 4, stream);

    qkv_gemm<<<768, 256, 0, stream>>>(xF, WqF, WkF, WvF,
                                      bq, bk, bv, QF, KF, VtF, km2);

    flash_attn<<<512, 256, 0, stream>>>(QF, KF, VtF, km2, AOF);

    gemm_out<<<256, 256, 0, stream>>>(AOF, WoF, bo, out);
}

// Round 3
// 407.817 us; speedup vs baseline: 1.1578x; 1.1578x over previous
//
#include <hip/hip_runtime.h>
#include <hip/hip_fp16.h>
#include <math.h>

#define D_MODEL 1024
#define NH 16
#define HD 64
#define SEQ 2048
#define BATCH 2
#define MROWS (BATCH*SEQ)   // 4096
#define KDIM 1024

typedef unsigned short u16;
typedef __attribute__((ext_vector_type(8))) _Float16 h8;   // 8 f16 (4 VGPRs)
typedef __attribute__((ext_vector_type(8))) short s8v;
typedef __attribute__((ext_vector_type(4))) float f4v;

#define MFMAH(a, b, c) __builtin_amdgcn_mfma_f32_16x16x32_f16(a, b, c, 0, 0, 0)

// async global->LDS DMA, 16B/lane; LDS dest must be wave-uniform base
__device__ __forceinline__ void gld16(const u16* g, u16* l) {
    __builtin_amdgcn_global_load_lds(
        (const __attribute__((address_space(1))) void*)g,
        (__attribute__((address_space(3))) void*)l, 16, 0, 0);
}

__device__ __forceinline__ u16 f32_to_f16(float f) {
    return __half_as_ushort(__float2half(f));   // v_cvt_f16_f32, RNE
}

// ---------------------------------------------------------------------------
// fp32 -> fp16 conversion for x (4M) + 4 W (1M each). 8 elems/thread.
// ---------------------------------------------------------------------------
__global__ __launch_bounds__(256)
void convert_f16(const float* __restrict__ x,
                 const float* __restrict__ Wq, const float* __restrict__ Wk,
                 const float* __restrict__ Wv, const float* __restrict__ Wo,
                 u16* __restrict__ xF,
                 u16* __restrict__ WqF, u16* __restrict__ WkF,
                 u16* __restrict__ WvF, u16* __restrict__ WoF) {
    int i = blockIdx.x * 256 + threadIdx.x;
    const float* src;
    u16* dst;
    int idx;
    if (i < (1 << 19)) {
        src = x; dst = xF; idx = i;
    } else {
        int j = i - (1 << 19);
        int w = j >> 17;
        idx = j & ((1 << 17) - 1);
        switch (w) {
            case 0:  src = Wq; dst = WqF; break;
            case 1:  src = Wk; dst = WkF; break;
            case 2:  src = Wv; dst = WvF; break;
            default: src = Wo; dst = WoF; break;
        }
    }
    float4 a = ((const float4*)src)[idx * 2];
    float4 b = ((const float4*)src)[idx * 2 + 1];
    s8v o;
    o[0] = (short)f32_to_f16(a.x); o[1] = (short)f32_to_f16(a.y);
    o[2] = (short)f32_to_f16(a.z); o[3] = (short)f32_to_f16(a.w);
    o[4] = (short)f32_to_f16(b.x); o[5] = (short)f32_to_f16(b.y);
    o[6] = (short)f32_to_f16(b.z); o[7] = (short)f32_to_f16(b.w);
    ((s8v*)dst)[idx] = o;
}

// ---------------------------------------------------------------------------
// Fused QKV fp16 MFMA GEMM — m97-style K-loop: global_load_lds width=16,
// double-buffered LDS (2 x 16KB), one barrier per K-step, prefetch before
// compute, 3 blocks/CU (grid 768 fully resident). XCD-swizzled 1D grid.
// Q,K: fused RoPE -> LDS-staged tile -> 16B/lane coalesced stores.
// K: atomicMax row-norm^2. V: LDS transpose -> fp16 [B,H,D,S].
// ---------------------------------------------------------------------------
__global__ __launch_bounds__(256, 3)
void qkv_gemm(const u16* __restrict__ xF, const u16* __restrict__ WqF,
              const u16* __restrict__ WkF, const u16* __restrict__ WvF,
              const float* __restrict__ bq, const float* __restrict__ bk,
              const float* __restrict__ bv,
              u16* __restrict__ QF, u16* __restrict__ KF,
              u16* __restrict__ VtF, float* __restrict__ km2) {
    __shared__ __align__(16) u16 SMEM[16384];   // 32 KB
    // buf0: A @0, B @4096 ; buf1: A @8192, B @12288  (u16 units)

    const int t    = threadIdx.x;
    const int w    = t >> 6;
    const int lane = t & 63;
    const int quad = lane >> 4;
    const int l15  = lane & 15;
    const int wr   = w >> 1;
    const int wc   = w & 1;

    // XCD-aware decode: xcd = bid&7 owns m-tiles [xcd*4, xcd*4+4)
    const int bid  = blockIdx.x;
    const int xcd  = bid & 7;
    const int j    = bid >> 3;          // 0..95
    const int m0b  = (xcd * 4 + (j & 3)) * 128;
    const int yt   = j >> 2;            // 0..23
    const int wsel = yt >> 3;
    const int n0   = (yt & 7) * 128;

    const u16* Bg;
    const float* bias;
    if (wsel == 0)      { Bg = WqF; bias = bq; }
    else if (wsel == 1) { Bg = WkF; bias = bk; }
    else                { Bg = WvF; bias = bv; }

    // staging geometry: wave w covers A/B rows [w*32, w*32+32) in 2 insts;
    // lane l -> row seg*16 + (l>>2), 16B chunk (l&3) of the 64B k-slice
    const int srA = lane >> 2;          // 0..15 row within 16-row segment
    const int scA = (lane & 3) * 8;     // u16 col within 32-col k-slice

    f4v acc[4][4];
    #pragma unroll
    for (int i = 0; i < 4; i++)
        #pragma unroll
        for (int jj = 0; jj < 4; jj++)
            acc[i][jj] = (f4v){0.f, 0.f, 0.f, 0.f};

    // prologue: stage k=0 into buf0
    #pragma unroll
    for (int jj = 0; jj < 2; jj++) {
        int seg = w * 2 + jj;           // 0..7
        int row = seg * 16 + srA;
        gld16(xF + (size_t)(m0b + row) * KDIM + scA, SMEM + seg * 512);
        gld16(Bg + (size_t)(n0 + row) * KDIM + scA, SMEM + 4096 + seg * 512);
    }
    __syncthreads();

    int buf = 0;
    for (int k0 = 0; k0 < KDIM; k0 += 32) {
        // prefetch next k-slice into the other buffer
        if (k0 + 32 < KDIM) {
            u16* dstA = SMEM + (buf ^ 1) * 8192;
            #pragma unroll
            for (int jj = 0; jj < 2; jj++) {
                int seg = w * 2 + jj;
                int row = seg * 16 + srA;
                gld16(xF + (size_t)(m0b + row) * KDIM + k0 + 32 + scA,
                      dstA + seg * 512);
                gld16(Bg + (size_t)(n0 + row) * KDIM + k0 + 32 + scA,
                      dstA + 4096 + seg * 512);
            }
        }

        const u16* As = SMEM + buf * 8192;
        const u16* Bs = As + 4096;
        h8 a[4], b[4];
        #pragma unroll
        for (int i = 0; i < 4; i++) {
            a[i] = *(const h8*)&As[(wr * 64 + i * 16 + l15) * 32 + quad * 8];
            b[i] = *(const h8*)&Bs[(wc * 64 + i * 16 + l15) * 32 + quad * 8];
        }
        #pragma unroll
        for (int mt = 0; mt < 4; mt++)
            #pragma unroll
            for (int nt = 0; nt < 4; nt++)
                acc[mt][nt] = MFMAH(a[mt], b[nt], acc[mt][nt]);

        __syncthreads();                // drains vmcnt+lgkm; next buf ready
        buf ^= 1;
    }

    const int bb = m0b >> 11;
    const int s0 = m0b & 2047;
    const int h0 = n0 >> 6;             // first of 2 heads in this n-tile

    if (wsel < 2) {
        // ---- Q/K: fused RoPE -> LDS tile [128 s][128 n] swizzled ----
        u16* OF = (wsel == 0) ? QF : KF;
        float kn_max = 0.f;
        #pragma unroll
        for (int mt = 0; mt < 4; mt++) {
            #pragma unroll
            for (int r = 0; r < 4; r++) {
                int row = wr * 64 + mt * 16 + quad * 4 + r;   // local s
                int s = (m0b + row) & 2047;
                float rowsum = 0.f;
                #pragma unroll
                for (int nt = 0; nt < 2; nt++) {
                    int col = wc * 64 + nt * 16 + l15;        // local n
                    int n1 = n0 + col;
                    int dd = n1 & 31;
                    float v1 = acc[mt][nt][r]     + bias[n1];
                    float v2 = acc[mt][nt + 2][r] + bias[n1 + 32];
                    float inv = __expf(-(float)dd * 0.2878231366f); // 1e4^(-dd/32)
                    float ang = (float)s * inv;
                    float cs  = cosf(ang);
                    float sn  = sinf(ang);
                    float r1 = v1 * cs - v2 * sn;
                    float r2 = v2 * cs + v1 * sn;
                    rowsum += v1 * v1 + v2 * v2;     // norm is RoPE-invariant
                    SMEM[row * 128 + (((col >> 3) ^ (row & 15)) << 3) + (col & 7)]
                        = f32_to_f16(r1);
                    int col2 = col + 32;
                    SMEM[row * 128 + (((col2 >> 3) ^ (row & 15)) << 3) + (col2 & 7)]
                        = f32_to_f16(r2);
                }
                if (wsel == 1) {
                    rowsum += __shfl_xor(rowsum, 1, 64);
                    rowsum += __shfl_xor(rowsum, 2, 64);
                    rowsum += __shfl_xor(rowsum, 4, 64);
                    rowsum += __shfl_xor(rowsum, 8, 64);
                    kn_max = fmaxf(kn_max, rowsum);
                }
            }
        }
        if (wsel == 1) {
            kn_max = fmaxf(kn_max, __shfl_xor(kn_max, 16, 64));
            kn_max = fmaxf(kn_max, __shfl_xor(kn_max, 32, 64));
            if (lane == 0) atomicMax((int*)km2, __float_as_int(kn_max));
        }
        __syncthreads();
        // drain: per instruction each wave writes 1 KB contiguous [B,H,S,D]
        #pragma unroll
        for (int cc = 0; cc < 8; cc++) {
            int idx  = cc * 256 + t;       // 0..2047
            int hl   = idx >> 10;          // 0..1
            int rem  = idx & 1023;
            int sr   = rem >> 3;           // local s 0..127
            int dch  = rem & 7;            // 16B chunk along d
            s8v val = *(const s8v*)&SMEM[sr * 128 +
                          (((hl * 8 + dch) ^ (sr & 15)) << 3)];
            *(s8v*)(OF + (((size_t)bb * NH + h0 + hl) * SEQ + s0 + sr) * 64
                       + dch * 8) = val;
        }
    } else {
        // ---- V: transpose via LDS, fp16 [B,H,D,S] ----
        #pragma unroll
        for (int mt = 0; mt < 4; mt++) {
            #pragma unroll
            for (int nt = 0; nt < 4; nt++) {
                int n = wc * 64 + nt * 16 + l15;
                float bv_ = bias[n0 + n];
                #pragma unroll
                for (int r = 0; r < 4; r++) {
                    int m = wr * 64 + mt * 16 + quad * 4 + r;
                    float v = acc[mt][nt][r] + bv_;
                    SMEM[n * 128 + ((((m >> 3) ^ (n & 15))) << 3) + (m & 7)] = f32_to_f16(v);
                }
            }
        }
        __syncthreads();
        // drain: per instruction a wave covers 4 full d-rows (4 x 256B)
        #pragma unroll
        for (int cc = 0; cc < 8; cc++) {
            int idx = cc * 256 + t;        // 0..2047
            int n   = idx >> 4;            // local col: h*64+d, 0..127
            int mc  = idx & 15;            // 16B chunk along s
            int d   = n & 63;
            int hh  = n >> 6;
            size_t obase = ((size_t)((bb * NH + h0 + hh) * HD + d)) * SEQ + s0;
            s8v val = *(const s8v*)&SMEM[n * 128 + ((mc ^ (n & 15)) << 3)];
            *(s8v*)(VtF + obase + mc * 8) = val;
        }
    }
}

// ---------------------------------------------------------------------------
// MFMA flash attention (round-0 fast version), fp16, static-bound softmax,
// Q-tile 128, 64 keys per barrier. XCD-swizzled 1D grid (512).
// ---------------------------------------------------------------------------
__global__ __launch_bounds__(256, 4)
void flash_attn(const u16* __restrict__ QF, const u16* __restrict__ KF,
                const u16* __restrict__ VtF,
                const float* __restrict__ kmax2,
                u16* __restrict__ AOF) {
    __shared__ __align__(16) u16 KS[2][32 * 72];
    __shared__ __align__(16) u16 VtS[2][64 * 40];
    __shared__ __align__(16) u16 PS[128 * 40];

    const int t    = threadIdx.x;
    const int w    = t >> 6;
    const int lane = t & 63;
    const int quad = lane >> 4;
    const int l15  = lane & 15;

    const int bid = blockIdx.x;
    const int xcd = bid & 7;
    const int j   = bid >> 3;          // 0..63
    const int bh  = xcd * 4 + (j & 3); // 0..31
    const int q0  = (j >> 2) * 128;    // 0..15 * 128

    const size_t kvbase = (size_t)bh * SEQ * HD;
    const float km2 = kmax2[0];

    // ---- Q fragments for both row-tiles; static softmax bounds ----
    h8 qf[2][2];
    float m0[2][4];
    #pragma unroll
    for (int g = 0; g < 2; g++) {
        const u16* qp = QF + kvbase +
            (size_t)(q0 + g * 64 + w * 16 + l15) * HD + quad * 8;
        qf[g][0] = *(const h8*)qp;
        qf[g][1] = *(const h8*)(qp + 32);
        float qn2 = 0.f;
        #pragma unroll
        for (int st = 0; st < 2; st++)
            #pragma unroll
            for (int e = 0; e < 8; e++) {
                float v = (float)qf[g][st][e];
                qn2 += v * v;
            }
        qn2 += __shfl_xor(qn2, 16, 64);
        qn2 += __shfl_xor(qn2, 32, 64);
        #pragma unroll
        for (int r = 0; r < 4; r++) {
            int src = (lane & 48) | (quad * 4 + r);
            float qr = __shfl(qn2, src, 64);
            m0[g][r] = sqrtf(qr * km2) * 0.125f;
        }
    }

    f4v o[2][4];
    float lsum[2][4];
    #pragma unroll
    for (int g = 0; g < 2; g++)
        #pragma unroll
        for (int nt = 0; nt < 4; nt++) {
            o[g][nt] = (f4v){0.f, 0.f, 0.f, 0.f};
            lsum[g][nt] = 0.f;
        }

    for (int k0 = 0; k0 < SEQ; k0 += 64) {
        __syncthreads();

        // ---- stage two K subtiles (each 32 keys x 64 d) ----
        {
            int row = t >> 3;
            int dc  = (t & 7) * 8;
            *(s8v*)&KS[0][row * 72 + dc] =
                *(const s8v*)(KF + kvbase + (size_t)(k0 + row) * HD + dc);
            *(s8v*)&KS[1][row * 72 + dc] =
                *(const s8v*)(KF + kvbase + (size_t)(k0 + 32 + row) * HD + dc);
        }
        // ---- stage two V subtiles (64 d x 32 keys, swizzled) ----
        {
            int d  = t >> 2;
            int kc = (t & 3) * 8;
            size_t g = (size_t)bh * HD * SEQ + (size_t)d * SEQ + k0 + kc;
            int col = kc ^ (((d >> 3) & 3) << 3);
            *(s8v*)&VtS[0][d * 40 + col] = *(const s8v*)(VtF + g);
            *(s8v*)&VtS[1][d * 40 + col] = *(const s8v*)(VtF + g + 32);
        }
        __syncthreads();

        #pragma unroll
        for (int sub = 0; sub < 2; sub++) {
            const u16* kb0 = KS[sub] + l15 * 72 + quad * 8;
            const u16* kb1 = KS[sub] + (16 + l15) * 72 + quad * 8;
            h8 kh0 = *(const h8*)kb0, kh1 = *(const h8*)(kb0 + 32);
            h8 kh2 = *(const h8*)kb1, kh3 = *(const h8*)(kb1 + 32);

            #pragma unroll
            for (int g = 0; g < 2; g++) {
                f4v s0 = (f4v){0.f, 0.f, 0.f, 0.f};
                f4v s1 = (f4v){0.f, 0.f, 0.f, 0.f};
                s0 = MFMAH(qf[g][0], kh0, s0);
                s0 = MFMAH(qf[g][1], kh1, s0);
                s1 = MFMAH(qf[g][0], kh2, s1);
                s1 = MFMAH(qf[g][1], kh3, s1);

                #pragma unroll
                for (int r = 0; r < 4; r++) {
                    float p0 = __expf(s0[r] * 0.125f - m0[g][r]);
                    float p1 = __expf(s1[r] * 0.125f - m0[g][r]);
                    lsum[g][r] += p0 + p1;
                    int row_l = g * 64 + w * 16 + quad * 4 + r;
                    int cs = row_l & 8;
                    PS[row_l * 40 + (l15 ^ cs)]        = f32_to_f16(p0);
                    PS[row_l * 40 + ((16 + l15) ^ cs)] = f32_to_f16(p1);
                }

                const int prow = g * 64 + w * 16 + l15;
                h8 ph = *(const h8*)&PS[prow * 40 + ((quad * 8) ^ (prow & 8))];
                #pragma unroll
                for (int nt = 0; nt < 4; nt++) {
                    int dim = nt * 16 + l15;
                    int voff = dim * 40 + ((quad * 8) ^ (((dim >> 3) & 3) << 3));
                    o[g][nt] = MFMAH(ph, *(const h8*)&VtS[sub][voff], o[g][nt]);
                }
            }
        }
    }

    // ---- epilogue: reduce l, normalize, write fp16 [B,S,H,D] ----
    const int b = bh >> 4;
    const int h = bh & 15;
    #pragma unroll
    for (int g = 0; g < 2; g++) {
        #pragma unroll
        for (int r = 0; r < 4; r++) {
            float l = lsum[g][r];
            l += __shfl_xor(l, 1, 64);
            l += __shfl_xor(l, 2, 64);
            l += __shfl_xor(l, 4, 64);
            l += __shfl_xor(l, 8, 64);
            float inv_l = 1.0f / l;
            int s = q0 + g * 64 + w * 16 + quad * 4 + r;
            size_t obase = (((size_t)b * SEQ + s) * NH + h) * HD;
            #pragma unroll
            for (int nt = 0; nt < 4; nt++) {
                AOF[obase + nt * 16 + l15] = f32_to_f16(o[g][nt][r] * inv_l);
            }
        }
    }
}

// ---------------------------------------------------------------------------
// Out-projection fp16 MFMA GEMM — same m97-style K-loop; direct f32 stores.
// ---------------------------------------------------------------------------
__global__ __launch_bounds__(256, 3)
void gemm_out(const u16* __restrict__ AF, const u16* __restrict__ BF,
              const float* __restrict__ bias, float* __restrict__ out) {
    __shared__ __align__(16) u16 SMEM[16384];   // 32 KB, double-buffered

    const int t    = threadIdx.x;
    const int w    = t >> 6;
    const int lane = t & 63;
    const int quad = lane >> 4;
    const int l15  = lane & 15;
    const int wr   = w >> 1;
    const int wc   = w & 1;

    const int bid = blockIdx.x;
    const int xcd = bid & 7;
    const int j   = bid >> 3;              // 0..31
    const int m0  = (xcd * 4 + (j & 3)) * 128;
    const int n0  = (j >> 2) * 128;        // 0..7 * 128

    const int srA = lane >> 2;
    const int scA = (lane & 3) * 8;

    f4v acc[4][4];
    #pragma unroll
    for (int i = 0; i < 4; i++)
        #pragma unroll
        for (int jj = 0; jj < 4; jj++)
            acc[i][jj] = (f4v){0.f, 0.f, 0.f, 0.f};

    #pragma unroll
    for (int jj = 0; jj < 2; jj++) {
        int seg = w * 2 + jj;
        int row = seg * 16 + srA;
        gld16(AF + (size_t)(m0 + row) * KDIM + scA, SMEM + seg * 512);
        gld16(BF + (size_t)(n0 + row) * KDIM + scA, SMEM + 4096 + seg * 512);
    }
    __syncthreads();

    int buf = 0;
    for (int k0 = 0; k0 < KDIM; k0 += 32) {
        if (k0 + 32 < KDIM) {
            u16* dstA = SMEM + (buf ^ 1) * 8192;
            #pragma unroll
            for (int jj = 0; jj < 2; jj++) {
                int seg = w * 2 + jj;
                int row = seg * 16 + srA;
                gld16(AF + (size_t)(m0 + row) * KDIM + k0 + 32 + scA,
                      dstA + seg * 512);
                gld16(BF + (size_t)(n0 + row) * KDIM + k0 + 32 + scA,
                      dstA + 4096 + seg * 512);
            }
        }

        const u16* As = SMEM + buf * 8192;
        const u16* Bs = As + 4096;
        h8 a[4], b[4];
        #pragma unroll
        for (int i = 0; i < 4; i++) {
            a[i] = *(const h8*)&As[(wr * 64 + i * 16 + l15) * 32 + quad * 8];
            b[i] = *(const h8*)&Bs[(wc * 64 + i * 16 + l15) * 32 + quad * 8];
        }
        #pragma unroll
        for (int mt = 0; mt < 4; mt++)
            #pragma unroll
            for (int nt = 0; nt < 4; nt++)
                acc[mt][nt] = MFMAH(a[mt], b[nt], acc[mt][nt]);

        __syncthreads();
        buf ^= 1;
    }

    #pragma unroll
    for (int mt = 0; mt < 4; mt++) {
        #pragma unroll
        for (int nt = 0; nt < 4; nt++) {
            int n = n0 + wc * 64 + nt * 16 + l15;
            float bv = bias[n];
            #pragma unroll
            for (int r = 0; r < 4; r++) {
                int m = m0 + wr * 64 + mt * 16 + quad * 4 + r;
                out[(size_t)m * 1024 + n] = acc[mt][nt][r] + bv;
            }
        }
    }
}

// ---------------------------------------------------------------------------
extern "C" void kernel_launch(void* const* d_in, const int* in_sizes, int n_in,
                              void* d_out, int out_size, void* d_ws, size_t ws_size,
                              hipStream_t stream) {
    const float* x  = (const float*)d_in[0];
    const float* Wq = (const float*)d_in[1];
    const float* bq = (const float*)d_in[2];
    const float* Wk = (const float*)d_in[3];
    const float* bk = (const float*)d_in[4];
    const float* Wv = (const float*)d_in[5];
    const float* bv = (const float*)d_in[6];
    const float* Wo = (const float*)d_in[7];
    const float* bo = (const float*)d_in[8];
    float* out = (float*)d_out;

    const size_t TEN = (size_t)MROWS * KDIM;     // 4,194,304
    const size_t WSZ = (size_t)KDIM * KDIM;      // 1,048,576

    u16* xF  = (u16*)d_ws;
    u16* WqF = xF + TEN;
    u16* WkF = WqF + WSZ;
    u16* WvF = WkF + WSZ;
    u16* WoF = WvF + WSZ;
    u16* QF  = WoF + WSZ;
    u16* KF  = QF + TEN;
    u16* VtF = KF + TEN;
    float* km2 = (float*)(VtF + TEN);
    u16* AOF = xF;          // x dead after qkv_gemm

    convert_f16<<<4096, 256, 0, stream>>>(x, Wq, Wk, Wv, Wo,
                                          xF, WqF, WkF, WvF, WoF);

    hipMemsetAsync(km2, 0, 4, stream);

    qkv_gemm<<<768, 256, 0, stream>>>(xF, WqF, WkF, WvF,
                                      bq, bk, bv, QF, KF, VtF, km2);

    flash_attn<<<512, 256, 0, stream>>>(QF, KF, VtF, km2, AOF);

    gemm_out<<<256, 256, 0, stream>>>(AOF, WoF, bo, out);
}

// Round 4
// 358.447 us; speedup vs baseline: 1.3173x; 1.1377x over previous
//
#include <hip/hip_runtime.h>
#include <hip/hip_fp16.h>
#include <math.h>

#define D_MODEL 1024
#define NH 16
#define HD 64
#define SEQ 2048
#define BATCH 2
#define MROWS (BATCH*SEQ)   // 4096
#define KDIM 1024

typedef unsigned short u16;
typedef __attribute__((ext_vector_type(8))) _Float16 h8;   // 8 f16 (4 VGPRs)
typedef __attribute__((ext_vector_type(8))) short s8v;
typedef __attribute__((ext_vector_type(4))) float f4v;

#define MFMAH(a, b, c) __builtin_amdgcn_mfma_f32_16x16x32_f16(a, b, c, 0, 0, 0)

// async global->LDS DMA, 16B/lane; LDS dest must be wave-uniform base
__device__ __forceinline__ void gld16(const u16* g, u16* l) {
    __builtin_amdgcn_global_load_lds(
        (const __attribute__((address_space(1))) void*)g,
        (__attribute__((address_space(3))) void*)l, 16, 0, 0);
}

__device__ __forceinline__ u16 f32_to_f16(float f) {
    return __half_as_ushort(__float2half(f));   // v_cvt_f16_f32, RNE
}

// ---------------------------------------------------------------------------
// fp32 -> fp16 conversion for x (4M) + 4 W (1M each). 8 elems/thread.
// ---------------------------------------------------------------------------
__global__ __launch_bounds__(256)
void convert_f16(const float* __restrict__ x,
                 const float* __restrict__ Wq, const float* __restrict__ Wk,
                 const float* __restrict__ Wv, const float* __restrict__ Wo,
                 u16* __restrict__ xF,
                 u16* __restrict__ WqF, u16* __restrict__ WkF,
                 u16* __restrict__ WvF, u16* __restrict__ WoF) {
    int i = blockIdx.x * 256 + threadIdx.x;
    const float* src;
    u16* dst;
    int idx;
    if (i < (1 << 19)) {
        src = x; dst = xF; idx = i;
    } else {
        int j = i - (1 << 19);
        int w = j >> 17;
        idx = j & ((1 << 17) - 1);
        switch (w) {
            case 0:  src = Wq; dst = WqF; break;
            case 1:  src = Wk; dst = WkF; break;
            case 2:  src = Wv; dst = WvF; break;
            default: src = Wo; dst = WoF; break;
        }
    }
    float4 a = ((const float4*)src)[idx * 2];
    float4 b = ((const float4*)src)[idx * 2 + 1];
    s8v o;
    o[0] = (short)f32_to_f16(a.x); o[1] = (short)f32_to_f16(a.y);
    o[2] = (short)f32_to_f16(a.z); o[3] = (short)f32_to_f16(a.w);
    o[4] = (short)f32_to_f16(b.x); o[5] = (short)f32_to_f16(b.y);
    o[6] = (short)f32_to_f16(b.z); o[7] = (short)f32_to_f16(b.w);
    ((s8v*)dst)[idx] = o;
}

// ---------------------------------------------------------------------------
// Fused QKV fp16 MFMA GEMM — BM=256 BN=128 BK=64, 16 barrier-iters (was 32),
// 64 MFMA/wave per barrier (was 16): amortizes the measured ~5.5k-cycle
// per-barrier cost. global_load_lds w=16, double-buffered 2x48KB, source-side
// XOR swizzle (chunk^row) so stride-128B fragment ds_read_b128 is
// conflict-free. Grid 384 (XCD-swizzled), 1 block/CU.
// Q,K: fused RoPE -> LDS-staged -> full-line stores. K: atomicMax row-norm^2.
// V: LDS transpose -> fp16 [B,H,D,S].
// ---------------------------------------------------------------------------
__global__ __launch_bounds__(256, 1)
void qkv_gemm(const u16* __restrict__ xF, const u16* __restrict__ WqF,
              const u16* __restrict__ WkF, const u16* __restrict__ WvF,
              const float* __restrict__ bq, const float* __restrict__ bk,
              const float* __restrict__ bv,
              u16* __restrict__ QF, u16* __restrict__ KF,
              u16* __restrict__ VtF, float* __restrict__ km2) {
    __shared__ __align__(16) u16 SMEM[49152];   // 96 KB
    // buf b: A [256][64] @ b*24576, B [128][64] @ b*24576+16384 (u16 units)

    const int t    = threadIdx.x;
    const int w    = t >> 6;
    const int lane = t & 63;
    const int quad = lane >> 4;
    const int l15  = lane & 15;
    const int wr   = w >> 1;        // m-half (128 rows)
    const int wc   = w & 1;         // n-half (64 cols)

    const int bid  = blockIdx.x;
    const int xcd  = bid & 7;
    const int j    = bid >> 3;          // 0..47
    const int m0   = (xcd * 2 + (j & 1)) * 256;
    const int yt   = j >> 1;            // 0..23
    const int wsel = yt >> 3;
    const int n0   = (yt & 7) * 128;

    const u16* Bg;
    const float* bias;
    if (wsel == 0)      { Bg = WqF; bias = bq; }
    else if (wsel == 1) { Bg = WkF; bias = bk; }
    else                { Bg = WvF; bias = bv; }

    // staging: one gld16 call = 1KB = 8 rows x 64 u16 (seg). LDS linear;
    // SOURCE chunk pre-swizzled: LDS(row, chunk p) holds global chunk p^(row&7)
    const int lr = lane >> 3;                 // row within seg
    const int lc = (((lane & 7) ^ lr)) * 8;   // swizzled global u16 col

    f4v acc[8][4];
    #pragma unroll
    for (int i = 0; i < 8; i++)
        #pragma unroll
        for (int jj = 0; jj < 4; jj++)
            acc[i][jj] = (f4v){0.f, 0.f, 0.f, 0.f};

#define STAGE(K0, DB) do {                                                   \
    u16* As_ = SMEM + (DB);                                                  \
    u16* Bs_ = As_ + 16384;                                                  \
    _Pragma("unroll")                                                        \
    for (int jj_ = 0; jj_ < 8; jj_++) {                                      \
        int seg = jj_ * 4 + w;                                               \
        gld16(xF + (size_t)(m0 + seg * 8 + lr) * KDIM + (K0) + lc,           \
              As_ + seg * 512);                                              \
    }                                                                        \
    _Pragma("unroll")                                                        \
    for (int jj_ = 0; jj_ < 4; jj_++) {                                      \
        int seg = jj_ * 4 + w;                                               \
        gld16(Bg + (size_t)(n0 + seg * 8 + lr) * KDIM + (K0) + lc,           \
              Bs_ + seg * 512);                                              \
    }                                                                        \
} while (0)

    STAGE(0, 0);
    __syncthreads();

    int buf = 0;
    for (int k0 = 0; k0 < KDIM; k0 += 64) {
        if (k0 + 64 < KDIM) STAGE(k0 + 64, (buf ^ 1) * 24576);

        const u16* As = SMEM + buf * 24576;
        const u16* Bs = As + 16384;
        #pragma unroll
        for (int kk = 0; kk < 2; kk++) {
            const int swz = ((kk * 4 + quad) ^ (l15 & 7)) << 3;
            h8 a[8], b[4];
            #pragma unroll
            for (int mt = 0; mt < 8; mt++)
                a[mt] = *(const h8*)&As[(wr * 128 + mt * 16 + l15) * 64 + swz];
            #pragma unroll
            for (int nt = 0; nt < 4; nt++)
                b[nt] = *(const h8*)&Bs[(wc * 64 + nt * 16 + l15) * 64 + swz];
            #pragma unroll
            for (int mt = 0; mt < 8; mt++)
                #pragma unroll
                for (int nt = 0; nt < 4; nt++)
                    acc[mt][nt] = MFMAH(a[mt], b[nt], acc[mt][nt]);
        }
        __syncthreads();
        buf ^= 1;
    }
#undef STAGE

    const int bb = m0 >> 11;            // batch (block never straddles)
    const int s0 = m0 & 2047;
    const int h0 = n0 >> 6;             // first of 2 heads in this n-tile

    if (wsel < 2) {
        // ---- Q/K: fused RoPE -> LDS tile [256 s][128 n] swizzled ----
        u16* OF = (wsel == 0) ? QF : KF;
        float kn_max = 0.f;
        #pragma unroll
        for (int mt = 0; mt < 8; mt++) {
            #pragma unroll
            for (int r = 0; r < 4; r++) {
                int R = wr * 128 + mt * 16 + quad * 4 + r;    // local s
                int s = s0 + R;
                float rowsum = 0.f;
                #pragma unroll
                for (int nt = 0; nt < 2; nt++) {
                    int col = wc * 64 + nt * 16 + l15;        // local n
                    int n1 = n0 + col;
                    int dd = n1 & 31;
                    float v1 = acc[mt][nt][r]     + bias[n1];
                    float v2 = acc[mt][nt + 2][r] + bias[n1 + 32];
                    float inv = __expf(-(float)dd * 0.2878231366f); // 1e4^(-dd/32)
                    float ang = (float)s * inv;
                    float cs  = cosf(ang);
                    float sn  = sinf(ang);
                    float r1 = v1 * cs - v2 * sn;
                    float r2 = v2 * cs + v1 * sn;
                    rowsum += v1 * v1 + v2 * v2;     // norm is RoPE-invariant
                    SMEM[R * 128 + (((col >> 3) ^ (R & 15)) << 3) + (col & 7)]
                        = f32_to_f16(r1);
                    int col2 = col + 32;
                    SMEM[R * 128 + (((col2 >> 3) ^ (R & 15)) << 3) + (col2 & 7)]
                        = f32_to_f16(r2);
                }
                if (wsel == 1) {
                    rowsum += __shfl_xor(rowsum, 1, 64);
                    rowsum += __shfl_xor(rowsum, 2, 64);
                    rowsum += __shfl_xor(rowsum, 4, 64);
                    rowsum += __shfl_xor(rowsum, 8, 64);
                    kn_max = fmaxf(kn_max, rowsum);
                }
            }
        }
        if (wsel == 1) {
            kn_max = fmaxf(kn_max, __shfl_xor(kn_max, 16, 64));
            kn_max = fmaxf(kn_max, __shfl_xor(kn_max, 32, 64));
            if (lane == 0) atomicMax((int*)km2, __float_as_int(kn_max));
        }
        __syncthreads();
        // drain 64KB: per instruction each wave writes 1 KB contiguous
        #pragma unroll
        for (int cc = 0; cc < 16; cc++) {
            int idx  = cc * 256 + t;       // 0..4095
            int hl   = idx >> 11;          // 0..1
            int rem  = idx & 2047;
            int R    = rem >> 3;           // local s 0..255
            int dch  = rem & 7;            // 16B chunk along d
            s8v val = *(const s8v*)&SMEM[R * 128 +
                          (((hl * 8 + dch) ^ (R & 15)) << 3)];
            *(s8v*)(OF + (((size_t)bb * NH + h0 + hl) * SEQ + s0 + R) * 64
                       + dch * 8) = val;
        }
    } else {
        // ---- V: transpose via LDS [128 n][256 m], fp16 [B,H,D,S] ----
        #pragma unroll
        for (int mt = 0; mt < 8; mt++) {
            #pragma unroll
            for (int nt = 0; nt < 4; nt++) {
                int n = wc * 64 + nt * 16 + l15;
                float bv_ = bias[n0 + n];
                #pragma unroll
                for (int r = 0; r < 4; r++) {
                    int m = wr * 128 + mt * 16 + quad * 4 + r;
                    float v = acc[mt][nt][r] + bv_;
                    SMEM[n * 256 + (((m >> 3) ^ (n & 31)) << 3) + (m & 7)]
                        = f32_to_f16(v);
                }
            }
        }
        __syncthreads();
        // drain: per instruction a wave covers 2 full d-rows (2 x 512B)
        #pragma unroll
        for (int cc = 0; cc < 16; cc++) {
            int idx = cc * 256 + t;        // 0..4095
            int n   = idx >> 5;            // local col: h*64+d, 0..127
            int mc  = idx & 31;            // 16B chunk along s
            int d   = n & 63;
            int hh  = n >> 6;
            size_t obase = ((size_t)((bb * NH + h0 + hh) * HD + d)) * SEQ + s0;
            s8v val = *(const s8v*)&SMEM[n * 256 + ((mc ^ (n & 31)) << 3)];
            *(s8v*)(VtF + obase + mc * 8) = val;
        }
    }
}

// ---------------------------------------------------------------------------
// MFMA flash attention (unchanged fast version), fp16, static-bound softmax,
// Q-tile 128, 64 keys per barrier. XCD-swizzled 1D grid (512).
// ---------------------------------------------------------------------------
__global__ __launch_bounds__(256, 4)
void flash_attn(const u16* __restrict__ QF, const u16* __restrict__ KF,
                const u16* __restrict__ VtF,
                const float* __restrict__ kmax2,
                u16* __restrict__ AOF) {
    __shared__ __align__(16) u16 KS[2][32 * 72];
    __shared__ __align__(16) u16 VtS[2][64 * 40];
    __shared__ __align__(16) u16 PS[128 * 40];

    const int t    = threadIdx.x;
    const int w    = t >> 6;
    const int lane = t & 63;
    const int quad = lane >> 4;
    const int l15  = lane & 15;

    const int bid = blockIdx.x;
    const int xcd = bid & 7;
    const int j   = bid >> 3;          // 0..63
    const int bh  = xcd * 4 + (j & 3); // 0..31
    const int q0  = (j >> 2) * 128;    // 0..15 * 128

    const size_t kvbase = (size_t)bh * SEQ * HD;
    const float km2 = kmax2[0];

    // ---- Q fragments for both row-tiles; static softmax bounds ----
    h8 qf[2][2];
    float m0[2][4];
    #pragma unroll
    for (int g = 0; g < 2; g++) {
        const u16* qp = QF + kvbase +
            (size_t)(q0 + g * 64 + w * 16 + l15) * HD + quad * 8;
        qf[g][0] = *(const h8*)qp;
        qf[g][1] = *(const h8*)(qp + 32);
        float qn2 = 0.f;
        #pragma unroll
        for (int st = 0; st < 2; st++)
            #pragma unroll
            for (int e = 0; e < 8; e++) {
                float v = (float)qf[g][st][e];
                qn2 += v * v;
            }
        qn2 += __shfl_xor(qn2, 16, 64);
        qn2 += __shfl_xor(qn2, 32, 64);
        #pragma unroll
        for (int r = 0; r < 4; r++) {
            int src = (lane & 48) | (quad * 4 + r);
            float qr = __shfl(qn2, src, 64);
            m0[g][r] = sqrtf(qr * km2) * 0.125f;
        }
    }

    f4v o[2][4];
    float lsum[2][4];
    #pragma unroll
    for (int g = 0; g < 2; g++)
        #pragma unroll
        for (int nt = 0; nt < 4; nt++) {
            o[g][nt] = (f4v){0.f, 0.f, 0.f, 0.f};
            lsum[g][nt] = 0.f;
        }

    for (int k0 = 0; k0 < SEQ; k0 += 64) {
        __syncthreads();

        // ---- stage two K subtiles (each 32 keys x 64 d) ----
        {
            int row = t >> 3;
            int dc  = (t & 7) * 8;
            *(s8v*)&KS[0][row * 72 + dc] =
                *(const s8v*)(KF + kvbase + (size_t)(k0 + row) * HD + dc);
            *(s8v*)&KS[1][row * 72 + dc] =
                *(const s8v*)(KF + kvbase + (size_t)(k0 + 32 + row) * HD + dc);
        }
        // ---- stage two V subtiles (64 d x 32 keys, swizzled) ----
        {
            int d  = t >> 2;
            int kc = (t & 3) * 8;
            size_t g = (size_t)bh * HD * SEQ + (size_t)d * SEQ + k0 + kc;
            int col = kc ^ (((d >> 3) & 3) << 3);
            *(s8v*)&VtS[0][d * 40 + col] = *(const s8v*)(VtF + g);
            *(s8v*)&VtS[1][d * 40 + col] = *(const s8v*)(VtF + g + 32);
        }
        __syncthreads();

        #pragma unroll
        for (int sub = 0; sub < 2; sub++) {
            const u16* kb0 = KS[sub] + l15 * 72 + quad * 8;
            const u16* kb1 = KS[sub] + (16 + l15) * 72 + quad * 8;
            h8 kh0 = *(const h8*)kb0, kh1 = *(const h8*)(kb0 + 32);
            h8 kh2 = *(const h8*)kb1, kh3 = *(const h8*)(kb1 + 32);

            #pragma unroll
            for (int g = 0; g < 2; g++) {
                f4v s0 = (f4v){0.f, 0.f, 0.f, 0.f};
                f4v s1 = (f4v){0.f, 0.f, 0.f, 0.f};
                s0 = MFMAH(qf[g][0], kh0, s0);
                s0 = MFMAH(qf[g][1], kh1, s0);
                s1 = MFMAH(qf[g][0], kh2, s1);
                s1 = MFMAH(qf[g][1], kh3, s1);

                #pragma unroll
                for (int r = 0; r < 4; r++) {
                    float p0 = __expf(s0[r] * 0.125f - m0[g][r]);
                    float p1 = __expf(s1[r] * 0.125f - m0[g][r]);
                    lsum[g][r] += p0 + p1;
                    int row_l = g * 64 + w * 16 + quad * 4 + r;
                    int cs = row_l & 8;
                    PS[row_l * 40 + (l15 ^ cs)]        = f32_to_f16(p0);
                    PS[row_l * 40 + ((16 + l15) ^ cs)] = f32_to_f16(p1);
                }

                const int prow = g * 64 + w * 16 + l15;
                h8 ph = *(const h8*)&PS[prow * 40 + ((quad * 8) ^ (prow & 8))];
                #pragma unroll
                for (int nt = 0; nt < 4; nt++) {
                    int dim = nt * 16 + l15;
                    int voff = dim * 40 + ((quad * 8) ^ (((dim >> 3) & 3) << 3));
                    o[g][nt] = MFMAH(ph, *(const h8*)&VtS[sub][voff], o[g][nt]);
                }
            }
        }
    }

    // ---- epilogue: reduce l, normalize, write fp16 [B,S,H,D] ----
    const int b = bh >> 4;
    const int h = bh & 15;
    #pragma unroll
    for (int g = 0; g < 2; g++) {
        #pragma unroll
        for (int r = 0; r < 4; r++) {
            float l = lsum[g][r];
            l += __shfl_xor(l, 1, 64);
            l += __shfl_xor(l, 2, 64);
            l += __shfl_xor(l, 4, 64);
            l += __shfl_xor(l, 8, 64);
            float inv_l = 1.0f / l;
            int s = q0 + g * 64 + w * 16 + quad * 4 + r;
            size_t obase = (((size_t)b * SEQ + s) * NH + h) * HD;
            #pragma unroll
            for (int nt = 0; nt < 4; nt++) {
                AOF[obase + nt * 16 + l15] = f32_to_f16(o[g][nt][r] * inv_l);
            }
        }
    }
}

// ---------------------------------------------------------------------------
// Out-projection fp16 MFMA GEMM — BM=256 BN=128 BK=64, grid 128,
// same amortized-barrier structure; direct f32 stores.
// ---------------------------------------------------------------------------
__global__ __launch_bounds__(256, 1)
void gemm_out(const u16* __restrict__ AF, const u16* __restrict__ BF,
              const float* __restrict__ bias, float* __restrict__ out) {
    __shared__ __align__(16) u16 SMEM[49152];   // 96 KB double-buffered

    const int t    = threadIdx.x;
    const int w    = t >> 6;
    const int lane = t & 63;
    const int quad = lane >> 4;
    const int l15  = lane & 15;
    const int wr   = w >> 1;
    const int wc   = w & 1;

    const int bid = blockIdx.x;
    const int xcd = bid & 7;
    const int j   = bid >> 3;              // 0..15
    const int m0  = (xcd * 2 + (j & 1)) * 256;
    const int n0  = (j >> 1) * 128;        // 0..7 * 128

    const int lr = lane >> 3;
    const int lc = (((lane & 7) ^ lr)) * 8;

    f4v acc[8][4];
    #pragma unroll
    for (int i = 0; i < 8; i++)
        #pragma unroll
        for (int jj = 0; jj < 4; jj++)
            acc[i][jj] = (f4v){0.f, 0.f, 0.f, 0.f};

#define STAGE(K0, DB) do {                                                   \
    u16* As_ = SMEM + (DB);                                                  \
    u16* Bs_ = As_ + 16384;                                                  \
    _Pragma("unroll")                                                        \
    for (int jj_ = 0; jj_ < 8; jj_++) {                                      \
        int seg = jj_ * 4 + w;                                               \
        gld16(AF + (size_t)(m0 + seg * 8 + lr) * KDIM + (K0) + lc,           \
              As_ + seg * 512);                                              \
    }                                                                        \
    _Pragma("unroll")                                                        \
    for (int jj_ = 0; jj_ < 4; jj_++) {                                      \
        int seg = jj_ * 4 + w;                                               \
        gld16(BF + (size_t)(n0 + seg * 8 + lr) * KDIM + (K0) + lc,           \
              Bs_ + seg * 512);                                              \
    }                                                                        \
} while (0)

    STAGE(0, 0);
    __syncthreads();

    int buf = 0;
    for (int k0 = 0; k0 < KDIM; k0 += 64) {
        if (k0 + 64 < KDIM) STAGE(k0 + 64, (buf ^ 1) * 24576);

        const u16* As = SMEM + buf * 24576;
        const u16* Bs = As + 16384;
        #pragma unroll
        for (int kk = 0; kk < 2; kk++) {
            const int swz = ((kk * 4 + quad) ^ (l15 & 7)) << 3;
            h8 a[8], b[4];
            #pragma unroll
            for (int mt = 0; mt < 8; mt++)
                a[mt] = *(const h8*)&As[(wr * 128 + mt * 16 + l15) * 64 + swz];
            #pragma unroll
            for (int nt = 0; nt < 4; nt++)
                b[nt] = *(const h8*)&Bs[(wc * 64 + nt * 16 + l15) * 64 + swz];
            #pragma unroll
            for (int mt = 0; mt < 8; mt++)
                #pragma unroll
                for (int nt = 0; nt < 4; nt++)
                    acc[mt][nt] = MFMAH(a[mt], b[nt], acc[mt][nt]);
        }
        __syncthreads();
        buf ^= 1;
    }
#undef STAGE

    #pragma unroll
    for (int mt = 0; mt < 8; mt++) {
        #pragma unroll
        for (int nt = 0; nt < 4; nt++) {
            int n = n0 + wc * 64 + nt * 16 + l15;
            float bv = bias[n];
            #pragma unroll
            for (int r = 0; r < 4; r++) {
                int m = m0 + wr * 128 + mt * 16 + quad * 4 + r;
                out[(size_t)m * 1024 + n] = acc[mt][nt][r] + bv;
            }
        }
    }
}

// ---------------------------------------------------------------------------
extern "C" void kernel_launch(void* const* d_in, const int* in_sizes, int n_in,
                              void* d_out, int out_size, void* d_ws, size_t ws_size,
                              hipStream_t stream) {
    const float* x  = (const float*)d_in[0];
    const float* Wq = (const float*)d_in[1];
    const float* bq = (const float*)d_in[2];
    const float* Wk = (const float*)d_in[3];
    const float* bk = (const float*)d_in[4];
    const float* Wv = (const float*)d_in[5];
    const float* bv = (const float*)d_in[6];
    const float* Wo = (const float*)d_in[7];
    const float* bo = (const float*)d_in[8];
    float* out = (float*)d_out;

    const size_t TEN = (size_t)MROWS * KDIM;     // 4,194,304
    const size_t WSZ = (size_t)KDIM * KDIM;      // 1,048,576

    u16* xF  = (u16*)d_ws;
    u16* WqF = xF + TEN;
    u16* WkF = WqF + WSZ;
    u16* WvF = WkF + WSZ;
    u16* WoF = WvF + WSZ;
    u16* QF  = WoF + WSZ;
    u16* KF  = QF + TEN;
    u16* VtF = KF + TEN;
    float* km2 = (float*)(VtF + TEN);
    u16* AOF = xF;          // x dead after qkv_gemm

    convert_f16<<<4096, 256, 0, stream>>>(x, Wq, Wk, Wv, Wo,
                                          xF, WqF, WkF, WvF, WoF);

    hipMemsetAsync(km2, 0, 4, stream);

    qkv_gemm<<<384, 256, 0, stream>>>(xF, WqF, WkF, WvF,
                                      bq, bk, bv, QF, KF, VtF, km2);

    flash_attn<<<512, 256, 0, stream>>>(QF, KF, VtF, km2, AOF);

    gemm_out<<<128, 256, 0, stream>>>(AOF, WoF, bo, out);
}

// Round 5
// 237.816 us; speedup vs baseline: 1.9854x; 1.5072x over previous
//
#include <hip/hip_runtime.h>
#include <hip/hip_fp16.h>
#include <math.h>

#define D_MODEL 1024
#define NH 16
#define HD 64
#define SEQ 2048
#define BATCH 2
#define MROWS (BATCH*SEQ)   // 4096
#define KDIM 1024

typedef unsigned short u16;
typedef __attribute__((ext_vector_type(8))) _Float16 h8;   // 8 f16 (4 VGPRs)
typedef __attribute__((ext_vector_type(8))) short s8v;
typedef __attribute__((ext_vector_type(4))) float f4v;

#define MFMAH(a, b, c) __builtin_amdgcn_mfma_f32_16x16x32_f16(a, b, c, 0, 0, 0)

// async global->LDS DMA, 16B/lane; LDS dest must be wave-uniform base
__device__ __forceinline__ void gld16(const u16* g, u16* l) {
    __builtin_amdgcn_global_load_lds(
        (const __attribute__((address_space(1))) void*)g,
        (__attribute__((address_space(3))) void*)l, 16, 0, 0);
}

__device__ __forceinline__ u16 f32_to_f16(float f) {
    return __half_as_ushort(__float2half(f));   // v_cvt_f16_f32, RNE
}

// ---------------------------------------------------------------------------
// fp32 -> fp16 conversion for x (4M) + 4 W (1M each), 8 elems/thread, PLUS
// RoPE cos/sin table build (blocks 4096..4351): ropeT[s*32+dd] — moves the
// 4M divergent large-arg sinf/cosf calls out of qkv_gemm's epilogue into a
// one-time 65k-entry table (512 KB, L2-resident).
// ---------------------------------------------------------------------------
__global__ __launch_bounds__(256)
void convert_f16(const float* __restrict__ x,
                 const float* __restrict__ Wq, const float* __restrict__ Wk,
                 const float* __restrict__ Wv, const float* __restrict__ Wo,
                 u16* __restrict__ xF,
                 u16* __restrict__ WqF, u16* __restrict__ WkF,
                 u16* __restrict__ WvF, u16* __restrict__ WoF,
                 float2* __restrict__ ropeT) {
    int i = blockIdx.x * 256 + threadIdx.x;
    if (i >= (1 << 20)) {
        // ---- RoPE table: s in [0,2048), dd in [0,32) ----
        int idx2 = i - (1 << 20);          // 0..65535
        int s  = idx2 >> 5;
        int dd = idx2 & 31;
        float inv = __expf(-(float)dd * 0.2878231366f);   // 1e4^(-dd/32)
        float ang = (float)s * inv;
        ropeT[idx2] = make_float2(cosf(ang), sinf(ang));  // same math as before
        return;
    }
    const float* src;
    u16* dst;
    int idx;
    if (i < (1 << 19)) {
        src = x; dst = xF; idx = i;
    } else {
        int j = i - (1 << 19);
        int w = j >> 17;
        idx = j & ((1 << 17) - 1);
        switch (w) {
            case 0:  src = Wq; dst = WqF; break;
            case 1:  src = Wk; dst = WkF; break;
            case 2:  src = Wv; dst = WvF; break;
            default: src = Wo; dst = WoF; break;
        }
    }
    float4 a = ((const float4*)src)[idx * 2];
    float4 b = ((const float4*)src)[idx * 2 + 1];
    s8v o;
    o[0] = (short)f32_to_f16(a.x); o[1] = (short)f32_to_f16(a.y);
    o[2] = (short)f32_to_f16(a.z); o[3] = (short)f32_to_f16(a.w);
    o[4] = (short)f32_to_f16(b.x); o[5] = (short)f32_to_f16(b.y);
    o[6] = (short)f32_to_f16(b.z); o[7] = (short)f32_to_f16(b.w);
    ((s8v*)dst)[idx] = o;
}

// ---------------------------------------------------------------------------
// Fused QKV fp16 MFMA GEMM — BM=256 BN=128 BK=64, global_load_lds w=16,
// double-buffered 2x48KB, source-side XOR swizzle. Grid 384 (XCD-swizzled).
// Q,K epilogue: RoPE via table lookup (was: per-element divergent
// cosf/sinf — the measured ~190us invariant) -> LDS-staged full-line stores.
// K: atomicMax row-norm^2. V: LDS transpose -> fp16 [B,H,D,S].
// ---------------------------------------------------------------------------
__global__ __launch_bounds__(256, 1)
void qkv_gemm(const u16* __restrict__ xF, const u16* __restrict__ WqF,
              const u16* __restrict__ WkF, const u16* __restrict__ WvF,
              const float* __restrict__ bq, const float* __restrict__ bk,
              const float* __restrict__ bv,
              const float2* __restrict__ ropeT,
              u16* __restrict__ QF, u16* __restrict__ KF,
              u16* __restrict__ VtF, float* __restrict__ km2) {
    __shared__ __align__(16) u16 SMEM[49152];   // 96 KB
    // buf b: A [256][64] @ b*24576, B [128][64] @ b*24576+16384 (u16 units)

    const int t    = threadIdx.x;
    const int w    = t >> 6;
    const int lane = t & 63;
    const int quad = lane >> 4;
    const int l15  = lane & 15;
    const int wr   = w >> 1;        // m-half (128 rows)
    const int wc   = w & 1;         // n-half (64 cols)

    const int bid  = blockIdx.x;
    const int xcd  = bid & 7;
    const int j    = bid >> 3;          // 0..47
    const int m0   = (xcd * 2 + (j & 1)) * 256;
    const int yt   = j >> 1;            // 0..23
    const int wsel = yt >> 3;
    const int n0   = (yt & 7) * 128;

    const u16* Bg;
    const float* bias;
    if (wsel == 0)      { Bg = WqF; bias = bq; }
    else if (wsel == 1) { Bg = WkF; bias = bk; }
    else                { Bg = WvF; bias = bv; }

    // staging: one gld16 call = 1KB = 8 rows x 64 u16 (seg). LDS linear;
    // SOURCE chunk pre-swizzled: LDS(row, chunk p) holds global chunk p^(row&7)
    const int lr = lane >> 3;                 // row within seg
    const int lc = (((lane & 7) ^ lr)) * 8;   // swizzled global u16 col

    f4v acc[8][4];
    #pragma unroll
    for (int i = 0; i < 8; i++)
        #pragma unroll
        for (int jj = 0; jj < 4; jj++)
            acc[i][jj] = (f4v){0.f, 0.f, 0.f, 0.f};

#define STAGE(K0, DB) do {                                                   \
    u16* As_ = SMEM + (DB);                                                  \
    u16* Bs_ = As_ + 16384;                                                  \
    _Pragma("unroll")                                                        \
    for (int jj_ = 0; jj_ < 8; jj_++) {                                      \
        int seg = jj_ * 4 + w;                                               \
        gld16(xF + (size_t)(m0 + seg * 8 + lr) * KDIM + (K0) + lc,           \
              As_ + seg * 512);                                              \
    }                                                                        \
    _Pragma("unroll")                                                        \
    for (int jj_ = 0; jj_ < 4; jj_++) {                                      \
        int seg = jj_ * 4 + w;                                               \
        gld16(Bg + (size_t)(n0 + seg * 8 + lr) * KDIM + (K0) + lc,           \
              Bs_ + seg * 512);                                              \
    }                                                                        \
} while (0)

    STAGE(0, 0);
    __syncthreads();

    int buf = 0;
    for (int k0 = 0; k0 < KDIM; k0 += 64) {
        if (k0 + 64 < KDIM) STAGE(k0 + 64, (buf ^ 1) * 24576);

        const u16* As = SMEM + buf * 24576;
        const u16* Bs = As + 16384;
        #pragma unroll
        for (int kk = 0; kk < 2; kk++) {
            const int swz = ((kk * 4 + quad) ^ (l15 & 7)) << 3;
            h8 a[8], b[4];
            #pragma unroll
            for (int mt = 0; mt < 8; mt++)
                a[mt] = *(const h8*)&As[(wr * 128 + mt * 16 + l15) * 64 + swz];
            #pragma unroll
            for (int nt = 0; nt < 4; nt++)
                b[nt] = *(const h8*)&Bs[(wc * 64 + nt * 16 + l15) * 64 + swz];
            #pragma unroll
            for (int mt = 0; mt < 8; mt++)
                #pragma unroll
                for (int nt = 0; nt < 4; nt++)
                    acc[mt][nt] = MFMAH(a[mt], b[nt], acc[mt][nt]);
        }
        __syncthreads();
        buf ^= 1;
    }
#undef STAGE

    const int bb = m0 >> 11;            // batch (block never straddles)
    const int s0 = m0 & 2047;
    const int h0 = n0 >> 6;             // first of 2 heads in this n-tile

    if (wsel < 2) {
        // ---- Q/K: fused RoPE (table) -> LDS tile [256 s][128 n] swizzled ----
        u16* OF = (wsel == 0) ? QF : KF;
        float kn_max = 0.f;
        #pragma unroll
        for (int mt = 0; mt < 8; mt++) {
            #pragma unroll
            for (int r = 0; r < 4; r++) {
                int R = wr * 128 + mt * 16 + quad * 4 + r;    // local s
                int s = s0 + R;
                float rowsum = 0.f;
                #pragma unroll
                for (int nt = 0; nt < 2; nt++) {
                    int col = wc * 64 + nt * 16 + l15;        // local n
                    int n1 = n0 + col;
                    int dd = n1 & 31;
                    float v1 = acc[mt][nt][r]     + bias[n1];
                    float v2 = acc[mt][nt + 2][r] + bias[n1 + 32];
                    float2 cssn = ropeT[(s << 5) | dd];       // coalesced 128B/quad
                    float cs  = cssn.x;
                    float sn  = cssn.y;
                    float r1 = v1 * cs - v2 * sn;
                    float r2 = v2 * cs + v1 * sn;
                    rowsum += v1 * v1 + v2 * v2;     // norm is RoPE-invariant
                    SMEM[R * 128 + (((col >> 3) ^ (R & 15)) << 3) + (col & 7)]
                        = f32_to_f16(r1);
                    int col2 = col + 32;
                    SMEM[R * 128 + (((col2 >> 3) ^ (R & 15)) << 3) + (col2 & 7)]
                        = f32_to_f16(r2);
                }
                if (wsel == 1) {
                    rowsum += __shfl_xor(rowsum, 1, 64);
                    rowsum += __shfl_xor(rowsum, 2, 64);
                    rowsum += __shfl_xor(rowsum, 4, 64);
                    rowsum += __shfl_xor(rowsum, 8, 64);
                    kn_max = fmaxf(kn_max, rowsum);
                }
            }
        }
        if (wsel == 1) {
            kn_max = fmaxf(kn_max, __shfl_xor(kn_max, 16, 64));
            kn_max = fmaxf(kn_max, __shfl_xor(kn_max, 32, 64));
            if (lane == 0) atomicMax((int*)km2, __float_as_int(kn_max));
        }
        __syncthreads();
        // drain 64KB: per instruction each wave writes 1 KB contiguous
        #pragma unroll
        for (int cc = 0; cc < 16; cc++) {
            int idx  = cc * 256 + t;       // 0..4095
            int hl   = idx >> 11;          // 0..1
            int rem  = idx & 2047;
            int R    = rem >> 3;           // local s 0..255
            int dch  = rem & 7;            // 16B chunk along d
            s8v val = *(const s8v*)&SMEM[R * 128 +
                          (((hl * 8 + dch) ^ (R & 15)) << 3)];
            *(s8v*)(OF + (((size_t)bb * NH + h0 + hl) * SEQ + s0 + R) * 64
                       + dch * 8) = val;
        }
    } else {
        // ---- V: transpose via LDS [128 n][256 m], fp16 [B,H,D,S] ----
        #pragma unroll
        for (int mt = 0; mt < 8; mt++) {
            #pragma unroll
            for (int nt = 0; nt < 4; nt++) {
                int n = wc * 64 + nt * 16 + l15;
                float bv_ = bias[n0 + n];
                #pragma unroll
                for (int r = 0; r < 4; r++) {
                    int m = wr * 128 + mt * 16 + quad * 4 + r;
                    float v = acc[mt][nt][r] + bv_;
                    SMEM[n * 256 + (((m >> 3) ^ (n & 31)) << 3) + (m & 7)]
                        = f32_to_f16(v);
                }
            }
        }
        __syncthreads();
        // drain: per instruction a wave covers 2 full d-rows (2 x 512B)
        #pragma unroll
        for (int cc = 0; cc < 16; cc++) {
            int idx = cc * 256 + t;        // 0..4095
            int n   = idx >> 5;            // local col: h*64+d, 0..127
            int mc  = idx & 31;            // 16B chunk along s
            int d   = n & 63;
            int hh  = n >> 6;
            size_t obase = ((size_t)((bb * NH + h0 + hh) * HD + d)) * SEQ + s0;
            s8v val = *(const s8v*)&SMEM[n * 256 + ((mc ^ (n & 31)) << 3)];
            *(s8v*)(VtF + obase + mc * 8) = val;
        }
    }
}

// ---------------------------------------------------------------------------
// MFMA flash attention (unchanged), fp16, static-bound softmax,
// Q-tile 128, 64 keys per barrier. XCD-swizzled 1D grid (512).
// ---------------------------------------------------------------------------
__global__ __launch_bounds__(256, 4)
void flash_attn(const u16* __restrict__ QF, const u16* __restrict__ KF,
                const u16* __restrict__ VtF,
                const float* __restrict__ kmax2,
                u16* __restrict__ AOF) {
    __shared__ __align__(16) u16 KS[2][32 * 72];
    __shared__ __align__(16) u16 VtS[2][64 * 40];
    __shared__ __align__(16) u16 PS[128 * 40];

    const int t    = threadIdx.x;
    const int w    = t >> 6;
    const int lane = t & 63;
    const int quad = lane >> 4;
    const int l15  = lane & 15;

    const int bid = blockIdx.x;
    const int xcd = bid & 7;
    const int j   = bid >> 3;          // 0..63
    const int bh  = xcd * 4 + (j & 3); // 0..31
    const int q0  = (j >> 2) * 128;    // 0..15 * 128

    const size_t kvbase = (size_t)bh * SEQ * HD;
    const float km2 = kmax2[0];

    // ---- Q fragments for both row-tiles; static softmax bounds ----
    h8 qf[2][2];
    float m0[2][4];
    #pragma unroll
    for (int g = 0; g < 2; g++) {
        const u16* qp = QF + kvbase +
            (size_t)(q0 + g * 64 + w * 16 + l15) * HD + quad * 8;
        qf[g][0] = *(const h8*)qp;
        qf[g][1] = *(const h8*)(qp + 32);
        float qn2 = 0.f;
        #pragma unroll
        for (int st = 0; st < 2; st++)
            #pragma unroll
            for (int e = 0; e < 8; e++) {
                float v = (float)qf[g][st][e];
                qn2 += v * v;
            }
        qn2 += __shfl_xor(qn2, 16, 64);
        qn2 += __shfl_xor(qn2, 32, 64);
        #pragma unroll
        for (int r = 0; r < 4; r++) {
            int src = (lane & 48) | (quad * 4 + r);
            float qr = __shfl(qn2, src, 64);
            m0[g][r] = sqrtf(qr * km2) * 0.125f;
        }
    }

    f4v o[2][4];
    float lsum[2][4];
    #pragma unroll
    for (int g = 0; g < 2; g++)
        #pragma unroll
        for (int nt = 0; nt < 4; nt++) {
            o[g][nt] = (f4v){0.f, 0.f, 0.f, 0.f};
            lsum[g][nt] = 0.f;
        }

    for (int k0 = 0; k0 < SEQ; k0 += 64) {
        __syncthreads();

        // ---- stage two K subtiles (each 32 keys x 64 d) ----
        {
            int row = t >> 3;
            int dc  = (t & 7) * 8;
            *(s8v*)&KS[0][row * 72 + dc] =
                *(const s8v*)(KF + kvbase + (size_t)(k0 + row) * HD + dc);
            *(s8v*)&KS[1][row * 72 + dc] =
                *(const s8v*)(KF + kvbase + (size_t)(k0 + 32 + row) * HD + dc);
        }
        // ---- stage two V subtiles (64 d x 32 keys, swizzled) ----
        {
            int d  = t >> 2;
            int kc = (t & 3) * 8;
            size_t g = (size_t)bh * HD * SEQ + (size_t)d * SEQ + k0 + kc;
            int col = kc ^ (((d >> 3) & 3) << 3);
            *(s8v*)&VtS[0][d * 40 + col] = *(const s8v*)(VtF + g);
            *(s8v*)&VtS[1][d * 40 + col] = *(const s8v*)(VtF + g + 32);
        }
        __syncthreads();

        #pragma unroll
        for (int sub = 0; sub < 2; sub++) {
            const u16* kb0 = KS[sub] + l15 * 72 + quad * 8;
            const u16* kb1 = KS[sub] + (16 + l15) * 72 + quad * 8;
            h8 kh0 = *(const h8*)kb0, kh1 = *(const h8*)(kb0 + 32);
            h8 kh2 = *(const h8*)kb1, kh3 = *(const h8*)(kb1 + 32);

            #pragma unroll
            for (int g = 0; g < 2; g++) {
                f4v s0 = (f4v){0.f, 0.f, 0.f, 0.f};
                f4v s1 = (f4v){0.f, 0.f, 0.f, 0.f};
                s0 = MFMAH(qf[g][0], kh0, s0);
                s0 = MFMAH(qf[g][1], kh1, s0);
                s1 = MFMAH(qf[g][0], kh2, s1);
                s1 = MFMAH(qf[g][1], kh3, s1);

                #pragma unroll
                for (int r = 0; r < 4; r++) {
                    float p0 = __expf(s0[r] * 0.125f - m0[g][r]);
                    float p1 = __expf(s1[r] * 0.125f - m0[g][r]);
                    lsum[g][r] += p0 + p1;
                    int row_l = g * 64 + w * 16 + quad * 4 + r;
                    int cs = row_l & 8;
                    PS[row_l * 40 + (l15 ^ cs)]        = f32_to_f16(p0);
                    PS[row_l * 40 + ((16 + l15) ^ cs)] = f32_to_f16(p1);
                }

                const int prow = g * 64 + w * 16 + l15;
                h8 ph = *(const h8*)&PS[prow * 40 + ((quad * 8) ^ (prow & 8))];
                #pragma unroll
                for (int nt = 0; nt < 4; nt++) {
                    int dim = nt * 16 + l15;
                    int voff = dim * 40 + ((quad * 8) ^ (((dim >> 3) & 3) << 3));
                    o[g][nt] = MFMAH(ph, *(const h8*)&VtS[sub][voff], o[g][nt]);
                }
            }
        }
    }

    // ---- epilogue: reduce l, normalize, write fp16 [B,S,H,D] ----
    const int b = bh >> 4;
    const int h = bh & 15;
    #pragma unroll
    for (int g = 0; g < 2; g++) {
        #pragma unroll
        for (int r = 0; r < 4; r++) {
            float l = lsum[g][r];
            l += __shfl_xor(l, 1, 64);
            l += __shfl_xor(l, 2, 64);
            l += __shfl_xor(l, 4, 64);
            l += __shfl_xor(l, 8, 64);
            float inv_l = 1.0f / l;
            int s = q0 + g * 64 + w * 16 + quad * 4 + r;
            size_t obase = (((size_t)b * SEQ + s) * NH + h) * HD;
            #pragma unroll
            for (int nt = 0; nt < 4; nt++) {
                AOF[obase + nt * 16 + l15] = f32_to_f16(o[g][nt][r] * inv_l);
            }
        }
    }
}

// ---------------------------------------------------------------------------
// Out-projection fp16 MFMA GEMM — BM=256 BN=128 BK=64, grid 128 (unchanged).
// ---------------------------------------------------------------------------
__global__ __launch_bounds__(256, 1)
void gemm_out(const u16* __restrict__ AF, const u16* __restrict__ BF,
              const float* __restrict__ bias, float* __restrict__ out) {
    __shared__ __align__(16) u16 SMEM[49152];   // 96 KB double-buffered

    const int t    = threadIdx.x;
    const int w    = t >> 6;
    const int lane = t & 63;
    const int quad = lane >> 4;
    const int l15  = lane & 15;
    const int wr   = w >> 1;
    const int wc   = w & 1;

    const int bid = blockIdx.x;
    const int xcd = bid & 7;
    const int j   = bid >> 3;              // 0..15
    const int m0  = (xcd * 2 + (j & 1)) * 256;
    const int n0  = (j >> 1) * 128;        // 0..7 * 128

    const int lr = lane >> 3;
    const int lc = (((lane & 7) ^ lr)) * 8;

    f4v acc[8][4];
    #pragma unroll
    for (int i = 0; i < 8; i++)
        #pragma unroll
        for (int jj = 0; jj < 4; jj++)
            acc[i][jj] = (f4v){0.f, 0.f, 0.f, 0.f};

#define STAGE(K0, DB) do {                                                   \
    u16* As_ = SMEM + (DB);                                                  \
    u16* Bs_ = As_ + 16384;                                                  \
    _Pragma("unroll")                                                        \
    for (int jj_ = 0; jj_ < 8; jj_++) {                                      \
        int seg = jj_ * 4 + w;                                               \
        gld16(AF + (size_t)(m0 + seg * 8 + lr) * KDIM + (K0) + lc,           \
              As_ + seg * 512);                                              \
    }                                                                        \
    _Pragma("unroll")                                                        \
    for (int jj_ = 0; jj_ < 4; jj_++) {                                      \
        int seg = jj_ * 4 + w;                                               \
        gld16(BF + (size_t)(n0 + seg * 8 + lr) * KDIM + (K0) + lc,           \
              Bs_ + seg * 512);                                              \
    }                                                                        \
} while (0)

    STAGE(0, 0);
    __syncthreads();

    int buf = 0;
    for (int k0 = 0; k0 < KDIM; k0 += 64) {
        if (k0 + 64 < KDIM) STAGE(k0 + 64, (buf ^ 1) * 24576);

        const u16* As = SMEM + buf * 24576;
        const u16* Bs = As + 16384;
        #pragma unroll
        for (int kk = 0; kk < 2; kk++) {
            const int swz = ((kk * 4 + quad) ^ (l15 & 7)) << 3;
            h8 a[8], b[4];
            #pragma unroll
            for (int mt = 0; mt < 8; mt++)
                a[mt] = *(const h8*)&As[(wr * 128 + mt * 16 + l15) * 64 + swz];
            #pragma unroll
            for (int nt = 0; nt < 4; nt++)
                b[nt] = *(const h8*)&Bs[(wc * 64 + nt * 16 + l15) * 64 + swz];
            #pragma unroll
            for (int mt = 0; mt < 8; mt++)
                #pragma unroll
                for (int nt = 0; nt < 4; nt++)
                    acc[mt][nt] = MFMAH(a[mt], b[nt], acc[mt][nt]);
        }
        __syncthreads();
        buf ^= 1;
    }
#undef STAGE

    #pragma unroll
    for (int mt = 0; mt < 8; mt++) {
        #pragma unroll
        for (int nt = 0; nt < 4; nt++) {
            int n = n0 + wc * 64 + nt * 16 + l15;
            float bv = bias[n];
            #pragma unroll
            for (int r = 0; r < 4; r++) {
                int m = m0 + wr * 128 + mt * 16 + quad * 4 + r;
                out[(size_t)m * 1024 + n] = acc[mt][nt][r] + bv;
            }
        }
    }
}

// ---------------------------------------------------------------------------
extern "C" void kernel_launch(void* const* d_in, const int* in_sizes, int n_in,
                              void* d_out, int out_size, void* d_ws, size_t ws_size,
                              hipStream_t stream) {
    const float* x  = (const float*)d_in[0];
    const float* Wq = (const float*)d_in[1];
    const float* bq = (const float*)d_in[2];
    const float* Wk = (const float*)d_in[3];
    const float* bk = (const float*)d_in[4];
    const float* Wv = (const float*)d_in[5];
    const float* bv = (const float*)d_in[6];
    const float* Wo = (const float*)d_in[7];
    const float* bo = (const float*)d_in[8];
    float* out = (float*)d_out;

    const size_t TEN = (size_t)MROWS * KDIM;     // 4,194,304
    const size_t WSZ = (size_t)KDIM * KDIM;      // 1,048,576

    u16* xF  = (u16*)d_ws;
    u16* WqF = xF + TEN;
    u16* WkF = WqF + WSZ;
    u16* WvF = WkF + WSZ;
    u16* WoF = WvF + WSZ;
    u16* QF  = WoF + WSZ;
    u16* KF  = QF + TEN;
    u16* VtF = KF + TEN;
    float* km2 = (float*)(VtF + TEN);
    float2* ropeT = (float2*)(km2 + 4);          // 2048*32 float2 = 512 KB
    u16* AOF = xF;          // x dead after qkv_gemm

    convert_f16<<<4352, 256, 0, stream>>>(x, Wq, Wk, Wv, Wo,
                                          xF, WqF, WkF, WvF, WoF, ropeT);

    hipMemsetAsync(km2, 0, 4, stream);

    qkv_gemm<<<384, 256, 0, stream>>>(xF, WqF, WkF, WvF,
                                      bq, bk, bv, ropeT, QF, KF, VtF, km2);

    flash_attn<<<512, 256, 0, stream>>>(QF, KF, VtF, km2, AOF);

    gemm_out<<<128, 256, 0, stream>>>(AOF, WoF, bo, out);
}

// Round 6
// 210.594 us; speedup vs baseline: 2.2421x; 1.1293x over previous
//
#include <hip/hip_runtime.h>
#include <hip/hip_fp16.h>
#include <math.h>

#define D_MODEL 1024
#define NH 16
#define HD 64
#define SEQ 2048
#define BATCH 2
#define MROWS (BATCH*SEQ)   // 4096
#define KDIM 1024

typedef unsigned short u16;
typedef __attribute__((ext_vector_type(8))) _Float16 h8;   // 8 f16 (4 VGPRs)
typedef __attribute__((ext_vector_type(8))) short s8v;
typedef __attribute__((ext_vector_type(4))) float f4v;

#define MFMAH(a, b, c) __builtin_amdgcn_mfma_f32_16x16x32_f16(a, b, c, 0, 0, 0)

// async global->LDS DMA, 16B/lane; LDS dest must be wave-uniform base
__device__ __forceinline__ void gld16(const u16* g, u16* l) {
    __builtin_amdgcn_global_load_lds(
        (const __attribute__((address_space(1))) void*)g,
        (__attribute__((address_space(3))) void*)l, 16, 0, 0);
}

__device__ __forceinline__ u16 f32_to_f16(float f) {
    return __half_as_ushort(__float2half(f));   // v_cvt_f16_f32, RNE
}

// ---------------------------------------------------------------------------
// fp32 -> fp16 conversion for x (4M) + 4 W (1M each), 8 elems/thread, PLUS
// RoPE cos/sin table build (blocks 4096..4351): ropeT[s*32+dd].
// ---------------------------------------------------------------------------
__global__ __launch_bounds__(256)
void convert_f16(const float* __restrict__ x,
                 const float* __restrict__ Wq, const float* __restrict__ Wk,
                 const float* __restrict__ Wv, const float* __restrict__ Wo,
                 u16* __restrict__ xF,
                 u16* __restrict__ WqF, u16* __restrict__ WkF,
                 u16* __restrict__ WvF, u16* __restrict__ WoF,
                 float2* __restrict__ ropeT) {
    int i = blockIdx.x * 256 + threadIdx.x;
    if (i >= (1 << 20)) {
        // ---- RoPE table: s in [0,2048), dd in [0,32) ----
        int idx2 = i - (1 << 20);          // 0..65535
        int s  = idx2 >> 5;
        int dd = idx2 & 31;
        float inv = __expf(-(float)dd * 0.2878231366f);   // 1e4^(-dd/32)
        float ang = (float)s * inv;
        ropeT[idx2] = make_float2(cosf(ang), sinf(ang));  // same math as before
        return;
    }
    const float* src;
    u16* dst;
    int idx;
    if (i < (1 << 19)) {
        src = x; dst = xF; idx = i;
    } else {
        int j = i - (1 << 19);
        int w = j >> 17;
        idx = j & ((1 << 17) - 1);
        switch (w) {
            case 0:  src = Wq; dst = WqF; break;
            case 1:  src = Wk; dst = WkF; break;
            case 2:  src = Wv; dst = WvF; break;
            default: src = Wo; dst = WoF; break;
        }
    }
    float4 a = ((const float4*)src)[idx * 2];
    float4 b = ((const float4*)src)[idx * 2 + 1];
    s8v o;
    o[0] = (short)f32_to_f16(a.x); o[1] = (short)f32_to_f16(a.y);
    o[2] = (short)f32_to_f16(a.z); o[3] = (short)f32_to_f16(a.w);
    o[4] = (short)f32_to_f16(b.x); o[5] = (short)f32_to_f16(b.y);
    o[6] = (short)f32_to_f16(b.z); o[7] = (short)f32_to_f16(b.w);
    ((s8v*)dst)[idx] = o;
}

// ---------------------------------------------------------------------------
// Fused QKV fp16 MFMA GEMM — BM=128 BN=128 BK=64, 64KB LDS dbuf ->
// 2 resident blocks/CU (8 waves/CU): cross-block latency hiding for the
// per-iter barrier drain (round-5 config was 1 wave/SIMD, 80% idle).
// global_load_lds w=16, source-side XOR swizzle. Grid 768, XCD-swizzled.
// Q,K: fused RoPE (table) -> LDS-staged full-line stores. K: atomicMax
// row-norm^2. V: LDS transpose -> fp16 [B,H,D,S].
// ---------------------------------------------------------------------------
__global__ __launch_bounds__(256, 2)
void qkv_gemm(const u16* __restrict__ xF, const u16* __restrict__ WqF,
              const u16* __restrict__ WkF, const u16* __restrict__ WvF,
              const float* __restrict__ bq, const float* __restrict__ bk,
              const float* __restrict__ bv,
              const float2* __restrict__ ropeT,
              u16* __restrict__ QF, u16* __restrict__ KF,
              u16* __restrict__ VtF, float* __restrict__ km2) {
    __shared__ __align__(16) u16 SMEM[32768];   // 64 KB
    // buf b: A [128][64] @ b*16384, B [128][64] @ b*16384+8192 (u16 units)

    const int t    = threadIdx.x;
    const int w    = t >> 6;
    const int lane = t & 63;
    const int quad = lane >> 4;
    const int l15  = lane & 15;
    const int wr   = w >> 1;        // m-half (64 rows)
    const int wc   = w & 1;         // n-half (64 cols)

    const int bid  = blockIdx.x;
    const int xcd  = bid & 7;
    const int j    = bid >> 3;          // 0..95
    const int m0   = (xcd * 4 + (j & 3)) * 128;
    const int yt   = j >> 2;            // 0..23
    const int wsel = yt >> 3;
    const int n0   = (yt & 7) * 128;

    const u16* Bg;
    const float* bias;
    if (wsel == 0)      { Bg = WqF; bias = bq; }
    else if (wsel == 1) { Bg = WkF; bias = bk; }
    else                { Bg = WvF; bias = bv; }

    // staging: one gld16 = 1KB = 8 rows x 64 u16 (seg). LDS linear;
    // SOURCE chunk pre-swizzled: LDS(row, chunk p) holds global chunk p^(row&7)
    const int lr = lane >> 3;                 // row within seg
    const int lc = (((lane & 7) ^ lr)) * 8;   // swizzled global u16 col

    f4v acc[4][4];
    #pragma unroll
    for (int i = 0; i < 4; i++)
        #pragma unroll
        for (int jj = 0; jj < 4; jj++)
            acc[i][jj] = (f4v){0.f, 0.f, 0.f, 0.f};

#define STAGE(K0, DB) do {                                                   \
    u16* As_ = SMEM + (DB);                                                  \
    u16* Bs_ = As_ + 8192;                                                   \
    _Pragma("unroll")                                                        \
    for (int jj_ = 0; jj_ < 4; jj_++) {                                      \
        int seg = jj_ * 4 + w;                                               \
        gld16(xF + (size_t)(m0 + seg * 8 + lr) * KDIM + (K0) + lc,           \
              As_ + seg * 512);                                              \
        gld16(Bg + (size_t)(n0 + seg * 8 + lr) * KDIM + (K0) + lc,           \
              Bs_ + seg * 512);                                              \
    }                                                                        \
} while (0)

    STAGE(0, 0);
    __syncthreads();

    int buf = 0;
    for (int k0 = 0; k0 < KDIM; k0 += 64) {
        if (k0 + 64 < KDIM) STAGE(k0 + 64, (buf ^ 1) * 16384);

        const u16* As = SMEM + buf * 16384;
        const u16* Bs = As + 8192;
        #pragma unroll
        for (int kk = 0; kk < 2; kk++) {
            const int swz = ((kk * 4 + quad) ^ (l15 & 7)) << 3;
            h8 a[4], b[4];
            #pragma unroll
            for (int mt = 0; mt < 4; mt++)
                a[mt] = *(const h8*)&As[(wr * 64 + mt * 16 + l15) * 64 + swz];
            #pragma unroll
            for (int nt = 0; nt < 4; nt++)
                b[nt] = *(const h8*)&Bs[(wc * 64 + nt * 16 + l15) * 64 + swz];
            #pragma unroll
            for (int mt = 0; mt < 4; mt++)
                #pragma unroll
                for (int nt = 0; nt < 4; nt++)
                    acc[mt][nt] = MFMAH(a[mt], b[nt], acc[mt][nt]);
        }
        __syncthreads();
        buf ^= 1;
    }
#undef STAGE

    const int bb = m0 >> 11;
    const int s0 = m0 & 2047;
    const int h0 = n0 >> 6;             // first of 2 heads in this n-tile

    if (wsel < 2) {
        // ---- Q/K: fused RoPE (table) -> LDS tile [128 s][128 n] swizzled ----
        u16* OF = (wsel == 0) ? QF : KF;
        float kn_max = 0.f;
        #pragma unroll
        for (int mt = 0; mt < 4; mt++) {
            #pragma unroll
            for (int r = 0; r < 4; r++) {
                int R = wr * 64 + mt * 16 + quad * 4 + r;     // local s
                int s = s0 + R;
                float rowsum = 0.f;
                #pragma unroll
                for (int nt = 0; nt < 2; nt++) {
                    int col = wc * 64 + nt * 16 + l15;        // local n
                    int n1 = n0 + col;
                    int dd = n1 & 31;
                    float v1 = acc[mt][nt][r]     + bias[n1];
                    float v2 = acc[mt][nt + 2][r] + bias[n1 + 32];
                    float2 cssn = ropeT[(s << 5) | dd];       // coalesced
                    float cs  = cssn.x;
                    float sn  = cssn.y;
                    float r1 = v1 * cs - v2 * sn;
                    float r2 = v2 * cs + v1 * sn;
                    rowsum += v1 * v1 + v2 * v2;     // norm is RoPE-invariant
                    SMEM[R * 128 + (((col >> 3) ^ (R & 15)) << 3) + (col & 7)]
                        = f32_to_f16(r1);
                    int col2 = col + 32;
                    SMEM[R * 128 + (((col2 >> 3) ^ (R & 15)) << 3) + (col2 & 7)]
                        = f32_to_f16(r2);
                }
                if (wsel == 1) {
                    rowsum += __shfl_xor(rowsum, 1, 64);
                    rowsum += __shfl_xor(rowsum, 2, 64);
                    rowsum += __shfl_xor(rowsum, 4, 64);
                    rowsum += __shfl_xor(rowsum, 8, 64);
                    kn_max = fmaxf(kn_max, rowsum);
                }
            }
        }
        if (wsel == 1) {
            kn_max = fmaxf(kn_max, __shfl_xor(kn_max, 16, 64));
            kn_max = fmaxf(kn_max, __shfl_xor(kn_max, 32, 64));
            if (lane == 0) atomicMax((int*)km2, __float_as_int(kn_max));
        }
        __syncthreads();
        // drain: per instruction each wave writes 1 KB contiguous [B,H,S,D]
        #pragma unroll
        for (int cc = 0; cc < 8; cc++) {
            int idx  = cc * 256 + t;       // 0..2047
            int hl   = idx >> 10;          // 0..1
            int rem  = idx & 1023;
            int R    = rem >> 3;           // local s 0..127
            int dch  = rem & 7;            // 16B chunk along d
            s8v val = *(const s8v*)&SMEM[R * 128 +
                          (((hl * 8 + dch) ^ (R & 15)) << 3)];
            *(s8v*)(OF + (((size_t)bb * NH + h0 + hl) * SEQ + s0 + R) * 64
                       + dch * 8) = val;
        }
    } else {
        // ---- V: transpose via LDS [128 n][128 m], fp16 [B,H,D,S] ----
        #pragma unroll
        for (int mt = 0; mt < 4; mt++) {
            #pragma unroll
            for (int nt = 0; nt < 4; nt++) {
                int n = wc * 64 + nt * 16 + l15;
                float bv_ = bias[n0 + n];
                #pragma unroll
                for (int r = 0; r < 4; r++) {
                    int m = wr * 64 + mt * 16 + quad * 4 + r;
                    float v = acc[mt][nt][r] + bv_;
                    SMEM[n * 128 + (((m >> 3) ^ (n & 15)) << 3) + (m & 7)]
                        = f32_to_f16(v);
                }
            }
        }
        __syncthreads();
        // drain: per instruction a wave covers 4 full d-rows (4 x 256B)
        #pragma unroll
        for (int cc = 0; cc < 8; cc++) {
            int idx = cc * 256 + t;        // 0..2047
            int n   = idx >> 4;            // local col: h*64+d, 0..127
            int mc  = idx & 15;            // 16B chunk along s
            int d   = n & 63;
            int hh  = n >> 6;
            size_t obase = ((size_t)((bb * NH + h0 + hh) * HD + d)) * SEQ + s0;
            s8v val = *(const s8v*)&SMEM[n * 128 + ((mc ^ (n & 15)) << 3)];
            *(s8v*)(VtF + obase + mc * 8) = val;
        }
    }
}

// ---------------------------------------------------------------------------
// MFMA flash attention, fp16, static-bound softmax. Q-tile 64 (was 128):
// grid 1024 -> 4 blocks/CU (16 waves/CU) for latency hiding. Same staging,
// softmax, and PV as the verified 128-row version minus the g dimension.
// ---------------------------------------------------------------------------
__global__ __launch_bounds__(256, 4)
void flash_attn(const u16* __restrict__ QF, const u16* __restrict__ KF,
                const u16* __restrict__ VtF,
                const float* __restrict__ kmax2,
                u16* __restrict__ AOF) {
    __shared__ __align__(16) u16 KS[2][32 * 72];
    __shared__ __align__(16) u16 VtS[2][64 * 40];
    __shared__ __align__(16) u16 PS[64 * 40];

    const int t    = threadIdx.x;
    const int w    = t >> 6;
    const int lane = t & 63;
    const int quad = lane >> 4;
    const int l15  = lane & 15;

    const int bid = blockIdx.x;
    const int xcd = bid & 7;
    const int j   = bid >> 3;          // 0..127
    const int bh  = xcd * 4 + (j & 3); // 0..31
    const int q0  = (j >> 2) * 64;     // 0..31 * 64

    const size_t kvbase = (size_t)bh * SEQ * HD;
    const float km2 = kmax2[0];

    // ---- Q fragments; static softmax bounds ----
    h8 qf[2];
    float mb[4];
    {
        const u16* qp = QF + kvbase +
            (size_t)(q0 + w * 16 + l15) * HD + quad * 8;
        qf[0] = *(const h8*)qp;
        qf[1] = *(const h8*)(qp + 32);
        float qn2 = 0.f;
        #pragma unroll
        for (int st = 0; st < 2; st++)
            #pragma unroll
            for (int e = 0; e < 8; e++) {
                float v = (float)qf[st][e];
                qn2 += v * v;
            }
        qn2 += __shfl_xor(qn2, 16, 64);
        qn2 += __shfl_xor(qn2, 32, 64);
        #pragma unroll
        for (int r = 0; r < 4; r++) {
            int src = (lane & 48) | (quad * 4 + r);
            float qr = __shfl(qn2, src, 64);
            mb[r] = sqrtf(qr * km2) * 0.125f;
        }
    }

    f4v o[4];
    float lsum[4];
    #pragma unroll
    for (int nt = 0; nt < 4; nt++) {
        o[nt] = (f4v){0.f, 0.f, 0.f, 0.f};
        lsum[nt] = 0.f;
    }

    for (int k0 = 0; k0 < SEQ; k0 += 64) {
        __syncthreads();

        // ---- stage two K subtiles (each 32 keys x 64 d) ----
        {
            int row = t >> 3;
            int dc  = (t & 7) * 8;
            *(s8v*)&KS[0][row * 72 + dc] =
                *(const s8v*)(KF + kvbase + (size_t)(k0 + row) * HD + dc);
            *(s8v*)&KS[1][row * 72 + dc] =
                *(const s8v*)(KF + kvbase + (size_t)(k0 + 32 + row) * HD + dc);
        }
        // ---- stage two V subtiles (64 d x 32 keys, swizzled) ----
        {
            int d  = t >> 2;
            int kc = (t & 3) * 8;
            size_t g = (size_t)bh * HD * SEQ + (size_t)d * SEQ + k0 + kc;
            int col = kc ^ (((d >> 3) & 3) << 3);
            *(s8v*)&VtS[0][d * 40 + col] = *(const s8v*)(VtF + g);
            *(s8v*)&VtS[1][d * 40 + col] = *(const s8v*)(VtF + g + 32);
        }
        __syncthreads();

        #pragma unroll
        for (int sub = 0; sub < 2; sub++) {
            const u16* kb0 = KS[sub] + l15 * 72 + quad * 8;
            const u16* kb1 = KS[sub] + (16 + l15) * 72 + quad * 8;
            h8 kh0 = *(const h8*)kb0, kh1 = *(const h8*)(kb0 + 32);
            h8 kh2 = *(const h8*)kb1, kh3 = *(const h8*)(kb1 + 32);

            f4v sc0 = (f4v){0.f, 0.f, 0.f, 0.f};
            f4v sc1 = (f4v){0.f, 0.f, 0.f, 0.f};
            sc0 = MFMAH(qf[0], kh0, sc0);
            sc0 = MFMAH(qf[1], kh1, sc0);
            sc1 = MFMAH(qf[0], kh2, sc1);
            sc1 = MFMAH(qf[1], kh3, sc1);

            #pragma unroll
            for (int r = 0; r < 4; r++) {
                float p0 = __expf(sc0[r] * 0.125f - mb[r]);
                float p1 = __expf(sc1[r] * 0.125f - mb[r]);
                lsum[r] += p0 + p1;
                int row_l = w * 16 + quad * 4 + r;
                int cs = row_l & 8;
                PS[row_l * 40 + (l15 ^ cs)]        = f32_to_f16(p0);
                PS[row_l * 40 + ((16 + l15) ^ cs)] = f32_to_f16(p1);
            }

            const int prow = w * 16 + l15;
            h8 ph = *(const h8*)&PS[prow * 40 + ((quad * 8) ^ (prow & 8))];
            #pragma unroll
            for (int nt = 0; nt < 4; nt++) {
                int dim = nt * 16 + l15;
                int voff = dim * 40 + ((quad * 8) ^ (((dim >> 3) & 3) << 3));
                o[nt] = MFMAH(ph, *(const h8*)&VtS[sub][voff], o[nt]);
            }
        }
    }

    // ---- epilogue: reduce l, normalize, write fp16 [B,S,H,D] ----
    const int b = bh >> 4;
    const int h = bh & 15;
    #pragma unroll
    for (int r = 0; r < 4; r++) {
        float l = lsum[r];
        l += __shfl_xor(l, 1, 64);
        l += __shfl_xor(l, 2, 64);
        l += __shfl_xor(l, 4, 64);
        l += __shfl_xor(l, 8, 64);
        float inv_l = 1.0f / l;
        int s = q0 + w * 16 + quad * 4 + r;
        size_t obase = (((size_t)b * SEQ + s) * NH + h) * HD;
        #pragma unroll
        for (int nt = 0; nt < 4; nt++) {
            AOF[obase + nt * 16 + l15] = f32_to_f16(o[nt][r] * inv_l);
        }
    }
}

// ---------------------------------------------------------------------------
// Out-projection fp16 MFMA GEMM — BM=128 BN=64 BK=64, grid 512 (2+ resident
// blocks/CU, all CUs covered; was grid 128 = half idle). Direct f32 stores.
// ---------------------------------------------------------------------------
__global__ __launch_bounds__(256, 2)
void gemm_out(const u16* __restrict__ AF, const u16* __restrict__ BF,
              const float* __restrict__ bias, float* __restrict__ out) {
    __shared__ __align__(16) u16 SMEM[24576];   // 48 KB
    // buf b: A [128][64] @ b*12288, B [64][64] @ b*12288+8192 (u16 units)

    const int t    = threadIdx.x;
    const int w    = t >> 6;
    const int lane = t & 63;
    const int quad = lane >> 4;
    const int l15  = lane & 15;
    const int wr   = w >> 1;        // m-half (64 rows)
    const int wc   = w & 1;         // n-half (32 cols)

    const int bid = blockIdx.x;
    const int xcd = bid & 7;
    const int j   = bid >> 3;              // 0..63
    const int m0  = (xcd * 4 + (j & 3)) * 128;
    const int n0  = (j >> 2) * 64;         // 0..15 * 64

    const int lr = lane >> 3;
    const int lc = (((lane & 7) ^ lr)) * 8;

    f4v acc[4][2];
    #pragma unroll
    for (int i = 0; i < 4; i++)
        #pragma unroll
        for (int jj = 0; jj < 2; jj++)
            acc[i][jj] = (f4v){0.f, 0.f, 0.f, 0.f};

#define STAGE(K0, DB) do {                                                   \
    u16* As_ = SMEM + (DB);                                                  \
    u16* Bs_ = As_ + 8192;                                                   \
    _Pragma("unroll")                                                        \
    for (int jj_ = 0; jj_ < 4; jj_++) {                                      \
        int seg = jj_ * 4 + w;                                               \
        gld16(AF + (size_t)(m0 + seg * 8 + lr) * KDIM + (K0) + lc,           \
              As_ + seg * 512);                                              \
    }                                                                        \
    _Pragma("unroll")                                                        \
    for (int jj_ = 0; jj_ < 2; jj_++) {                                      \
        int seg = jj_ * 4 + w;                                               \
        gld16(BF + (size_t)(n0 + seg * 8 + lr) * KDIM + (K0) + lc,           \
              Bs_ + seg * 512);                                              \
    }                                                                        \
} while (0)

    STAGE(0, 0);
    __syncthreads();

    int buf = 0;
    for (int k0 = 0; k0 < KDIM; k0 += 64) {
        if (k0 + 64 < KDIM) STAGE(k0 + 64, (buf ^ 1) * 12288);

        const u16* As = SMEM + buf * 12288;
        const u16* Bs = As + 8192;
        #pragma unroll
        for (int kk = 0; kk < 2; kk++) {
            const int swz = ((kk * 4 + quad) ^ (l15 & 7)) << 3;
            h8 a[4], b[2];
            #pragma unroll
            for (int mt = 0; mt < 4; mt++)
                a[mt] = *(const h8*)&As[(wr * 64 + mt * 16 + l15) * 64 + swz];
            #pragma unroll
            for (int nt = 0; nt < 2; nt++)
                b[nt] = *(const h8*)&Bs[(wc * 32 + nt * 16 + l15) * 64 + swz];
            #pragma unroll
            for (int mt = 0; mt < 4; mt++)
                #pragma unroll
                for (int nt = 0; nt < 2; nt++)
                    acc[mt][nt] = MFMAH(a[mt], b[nt], acc[mt][nt]);
        }
        __syncthreads();
        buf ^= 1;
    }
#undef STAGE

    #pragma unroll
    for (int mt = 0; mt < 4; mt++) {
        #pragma unroll
        for (int nt = 0; nt < 2; nt++) {
            int n = n0 + wc * 32 + nt * 16 + l15;
            float bv = bias[n];
            #pragma unroll
            for (int r = 0; r < 4; r++) {
                int m = m0 + wr * 64 + mt * 16 + quad * 4 + r;
                out[(size_t)m * 1024 + n] = acc[mt][nt][r] + bv;
            }
        }
    }
}

// ---------------------------------------------------------------------------
extern "C" void kernel_launch(void* const* d_in, const int* in_sizes, int n_in,
                              void* d_out, int out_size, void* d_ws, size_t ws_size,
                              hipStream_t stream) {
    const float* x  = (const float*)d_in[0];
    const float* Wq = (const float*)d_in[1];
    const float* bq = (const float*)d_in[2];
    const float* Wk = (const float*)d_in[3];
    const float* bk = (const float*)d_in[4];
    const float* Wv = (const float*)d_in[5];
    const float* bv = (const float*)d_in[6];
    const float* Wo = (const float*)d_in[7];
    const float* bo = (const float*)d_in[8];
    float* out = (float*)d_out;

    const size_t TEN = (size_t)MROWS * KDIM;     // 4,194,304
    const size_t WSZ = (size_t)KDIM * KDIM;      // 1,048,576

    u16* xF  = (u16*)d_ws;
    u16* WqF = xF + TEN;
    u16* WkF = WqF + WSZ;
    u16* WvF = WkF + WSZ;
    u16* WoF = WvF + WSZ;
    u16* QF  = WoF + WSZ;
    u16* KF  = QF + TEN;
    u16* VtF = KF + TEN;
    float* km2 = (float*)(VtF + TEN);
    float2* ropeT = (float2*)(km2 + 4);          // 2048*32 float2 = 512 KB
    u16* AOF = xF;          // x dead after qkv_gemm

    convert_f16<<<4352, 256, 0, stream>>>(x, Wq, Wk, Wv, Wo,
                                          xF, WqF, WkF, WvF, WoF, ropeT);

    hipMemsetAsync(km2, 0, 4, stream);

    qkv_gemm<<<768, 256, 0, stream>>>(xF, WqF, WkF, WvF,
                                      bq, bk, bv, ropeT, QF, KF, VtF, km2);

    flash_attn<<<1024, 256, 0, stream>>>(QF, KF, VtF, km2, AOF);

    gemm_out<<<512, 256, 0, stream>>>(AOF, WoF, bo, out);
}